// Round 11
// baseline (14943.552 us; speedup 1.0000x reference)
//
#include <hip/hip_runtime.h>
#include <stdint.h>
#include <math.h>

#define NCLS 80
#define TOTHW 20267
#define WLAYER 1179648ull  // shorts per packed layer: 18*16*8*64*8

typedef _Float16 f16x8 __attribute__((ext_vector_type(8)));
typedef float f32x4 __attribute__((ext_vector_type(4)));
typedef short s16x8 __attribute__((ext_vector_type(8)));

static constexpr int cLW[5]    = {152,76,38,19,10};
static constexpr int cLH[5]    = {100,50,25,13,7};
static constexpr int cLHW[5]   = {15200,3800,950,247,70};
static constexpr int cLCUM[5]  = {0,15200,19000,19950,20197};
static constexpr int cLSTR[5]  = {8,16,32,64,128};
static constexpr int cCB[11]   = {0,123,246,278,310,319,328,331,334,335,336};
static constexpr int cPBASE[11]= {0,15744,31488,35584,39680,40832,41984,42368,42752,42880,43008};
static constexpr int cRCUM[11] = {0,100,200,250,300,325,350,363,376,383,390};
static constexpr int cCPX64[6] = {0,475,594,624,632,635};
#define NPXB64 635
#define SBE 11010048ull   // 43008*256 elements per split buffer

// ---------------- helpers ----------------
// fp32 -> fp16 pair with scaled residual: x ~= h0 + h1 * 2^-11  (error <= 2^-24 |x|)
__device__ __forceinline__ void split2(float y, unsigned short& h0, unsigned short& h1) {
  _Float16 b0 = (_Float16)y;
  float f0 = (float)b0;
  _Float16 b1 = (_Float16)((y - f0) * 2048.0f);
  h0 = __builtin_bit_cast(unsigned short, b0);
  h1 = __builtin_bit_cast(unsigned short, b1);
}

__device__ __forceinline__ void lds_hist_add(uint32_t* h, uint32_t bucket) {
  unsigned long long act = __ballot(1);
  int lane = (int)(threadIdx.x & 63u);
  int leader = __ffsll(act) - 1;
  uint32_t lb = (uint32_t)__shfl((int)bucket, leader, 64);
  unsigned long long same = __ballot(bucket == lb);
  if (same == act) {
    if (lane == leader) atomicAdd(&h[bucket], (uint32_t)__popcll(act));
  } else {
    atomicAdd(&h[bucket], 1u);
  }
}

// ---------------- zero borders/gaps of a split-pair region (px-major) ----------------
__global__ void k_zero(unsigned short* X0, unsigned short* X1) {
  int px = blockIdx.x * 256 + threadIdx.x;
  if (px >= 43008) return;
  int pi = 0;
#pragma unroll
  for (int i = 1; i < 10; i++) if (px >= cPBASE[i]) pi = i;
  const int l = pi >> 1;
  const int p = px - cPBASE[pi];
  const int W = cLW[l], H = cLH[l], PWl = W + 2;
  const int pr = p / PWl, pc = p - pr * PWl;
  if (pr >= 1 && pr <= H && pc >= 1 && pc <= W) return;  // interior: left alone
  s16x8 z = {0,0,0,0,0,0,0,0};
  size_t base = (size_t)px * 256;
#pragma unroll
  for (int k = 0; k < 32; k++) {
    *reinterpret_cast<s16x8*>(X0 + base + k*8) = z;
    *reinterpret_cast<s16x8*>(X1 + base + k*8) = z;
  }
}

// ---------------- stage inputs -> padded px-major fp16 splits ----------------
__global__ __launch_bounds__(256)
void k_prep(const float* __restrict__ p0, const float* __restrict__ p1,
            const float* __restrict__ p2, const float* __restrict__ p3,
            const float* __restrict__ p4,
            unsigned short* __restrict__ X0, unsigned short* __restrict__ X1) {
  int bx = blockIdx.x;
  int pi = 0;
#pragma unroll
  for (int i = 1; i < 10; i++) if (bx >= cRCUM[i]) pi = i;
  const int h = bx - cRCUM[pi];
  const int l = pi >> 1, bidx = pi & 1;
  const int W = cLW[l], HW = cLHW[l], PWl = W + 2;
  const int PB = cPBASE[pi];
  const float* src;
  if (l == 0) src = p0; else if (l == 1) src = p1; else if (l == 2) src = p2;
  else if (l == 3) src = p3; else src = p4;
  src += (size_t)bidx * 256 * HW;
  const int tid = threadIdx.x;
  __shared__ float tile[64][152];
  for (int c0 = 0; c0 < 256; c0 += 64) {
    {
      int c = tid >> 2, wq = tid & 3;
      for (int w = wq; w < W; w += 4)
        tile[c][w] = src[(size_t)(c0 + c) * HW + h * W + w];
    }
    __syncthreads();
    {
      int c8 = (tid & 7) * 8;
      for (int w = tid >> 3; w < W; w += 32) {
        size_t base = (size_t)(PB + (h + 1) * PWl + (w + 1)) * 256 + c0 + c8;
        unsigned short a0[8], a1[8];
#pragma unroll
        for (int j = 0; j < 8; j++) split2(tile[c8 + j][w], a0[j], a1[j]);
        *reinterpret_cast<s16x8*>(X0 + base) = *reinterpret_cast<s16x8*>(a0);
        *reinterpret_cast<s16x8*>(X1 + base) = *reinterpret_cast<s16x8*>(a1);
      }
    }
    __syncthreads();
  }
}

// ---------------- pack ALL weights -> fragment-order fp16 splits ----------------
// layout: [layer][(r*2+s)][ocf(16)][kc(8)][lane(64)][8]
__global__ void k_packall(const float* __restrict__ box_w, const float* __restrict__ cls_w,
                          const float* __restrict__ logit_w, unsigned short* __restrict__ wp) {
  const int layer = blockIdx.y;
  const int oc = blockIdx.x, c = threadIdx.x;
  const float* w; int Cout = 256;
  const size_t WSTRIDE = (size_t)256 * 2304;
  if (layer < 4)      w = box_w + (size_t)layer * WSTRIDE;
  else if (layer < 8) w = cls_w + (size_t)(layer - 4) * WSTRIDE;
  else { w = logit_w; Cout = NCLS; }
  if (oc >= Cout) return;
  unsigned short* wpL = wp + (size_t)layer * WLAYER;
  const int ocf = oc >> 4, ln = oc & 15;
  const int kc = c >> 5, kg = (c >> 3) & 3, e = c & 7;
  const int lane = kg * 16 + ln;
#pragma unroll
  for (int r = 0; r < 9; r++) {
    float v = w[((size_t)oc * 256 + c) * 9 + r];
    unsigned short h0, h1;
    split2(v, h0, h1);
    wpL[((((size_t)(r * 2 + 0) * 16 + ocf) * 8 + kc) * 64 + lane) * 8 + e] = h0;
    wpL[((((size_t)(r * 2 + 1) * 16 + ocf) * 8 + kc) * 64 + lane) * 8 + e] = h1;
  }
}

// ---------------- pack head weights -> wh[r][c][5] ----------------
__global__ void k_packhead(const float* __restrict__ ctw, const float* __restrict__ pdw,
                           float* __restrict__ wh) {
  const int r = blockIdx.x, c = threadIdx.x;
  float* d = &wh[((size_t)r * 256 + c) * 5];
  d[0] = ctw[c * 9 + r];
#pragma unroll
  for (int q = 0; q < 4; q++) d[1 + q] = pdw[(size_t)q * 2304 + c * 9 + r];
}

// ---------------- MFMA conv v4 (256-thr, fallback + logits) ----------------
struct MfArgs {
  const unsigned short *X0, *X1;
  const unsigned short *Wp;
  const float* bias;
  unsigned short *Y0, *Y1;
  float* actf;
  float* scores;
  const float* ctrp;
  uint32_t* hist;
};

template<int EPI>
__global__ __launch_bounds__(256, 2)
void conv_mfma(MfArgs a) {
  __shared__ __align__(16) unsigned short lds[18432];
  const int tid = threadIdx.x;
  const int lane = tid & 63;
  const int wid = tid >> 6;

  const int nwg = (EPI == 2) ? 336 : 672;
  const int id = blockIdx.x;
  const int w = (id & 7) * (nwg >> 3) + (id >> 3);
  const int oc0 = (EPI == 2) ? 0 : (w & 1) * 128;
  int bx = (EPI == 2) ? w : (w >> 1);

  int pi = 0;
#pragma unroll
  for (int i = 1; i < 10; i++) if (bx >= cCB[i]) pi = i;
  const int l = pi >> 1, bidx = pi & 1;
  const int pxb = bx - cCB[pi];
  const int px0 = pxb * 128;
  const int PB = cPBASE[pi];
  const int W = cLW[l], H = cLH[l], HW = cLHW[l], PWl = W + 2;

  int row_[2], g_[2];
#pragma unroll
  for (int d = 0; d < 2; d++) {
    int idx2 = tid + d * 256;
    row_[d] = idx2 >> 2;
    g_[d] = idx2 & 3;
  }

  const int wr = wid >> 1, wc = wid & 1;
  const int kg = lane >> 4, ln15 = lane & 15;
  int fA[4];
#pragma unroll
  for (int mt = 0; mt < 4; mt++) fA[mt] = (wr * 64 + mt * 16 + ln15) * 72 + kg * 8;
  const int ocfb = (oc0 >> 4) + wc * 4;

  f32x4 acc0[4][4], acc1[4][4];
#pragma unroll
  for (int mt = 0; mt < 4; mt++)
#pragma unroll
    for (int nt = 0; nt < 4; nt++) {
      acc0[mt][nt] = (f32x4){0.f, 0.f, 0.f, 0.f};
      acc1[mt][nt] = (f32x4){0.f, 0.f, 0.f, 0.f};
    }

  s16x8 ra[4];
  auto loadA = [&](int step) {
    const int rr = step >> 3;
    const int c0 = (step & 7) << 5;
    const int dh = rr / 3 - 1, dw = rr - (rr / 3) * 3 - 1;
    const long long OFF = (long long)(PB + px0 + dh * PWl + dw);
#pragma unroll
    for (int s = 0; s < 2; s++) {
      const unsigned short* Xs = (s == 0) ? a.X0 : a.X1;
#pragma unroll
      for (int d = 0; d < 2; d++)
        ra[s * 2 + d] = *reinterpret_cast<const s16x8*>(Xs + (OFF + row_[d]) * 256 + c0 + g_[d] * 8);
    }
  };
  auto writeA = [&](int buf) {
#pragma unroll
    for (int s = 0; s < 2; s++)
#pragma unroll
      for (int d = 0; d < 2; d++) {
        const int o = buf * 9216 + row_[d] * 72 + (s * 4 + g_[d]) * 8;
        *reinterpret_cast<s16x8*>(&lds[o]) = ra[s * 2 + d];
      }
  };
  auto loadB = [&](int step, f16x8* bv) {
    const int rr = step >> 3, cc = step & 7;
#pragma unroll
    for (int nt = 0; nt < 4; nt++) {
      const size_t bo = ((size_t)((rr * 2) * 16 + ocfb + nt) * 8 + cc) * 512 + lane * 8;
      bv[nt * 2 + 0] = *reinterpret_cast<const f16x8*>(a.Wp + bo);
      bv[nt * 2 + 1] = *reinterpret_cast<const f16x8*>(a.Wp + bo + 65536);
    }
  };
  auto mfmaStep = [&](int buf, const f16x8* bv) {
    f16x8 av[4][2];
#pragma unroll
    for (int mt = 0; mt < 4; mt++) {
      av[mt][0] = *reinterpret_cast<const f16x8*>(&lds[buf * 9216 + fA[mt]]);
      av[mt][1] = *reinterpret_cast<const f16x8*>(&lds[buf * 9216 + fA[mt] + 32]);
    }
#pragma unroll
    for (int mt = 0; mt < 4; mt++)
#pragma unroll
      for (int nt = 0; nt < 4; nt++) {
        acc0[mt][nt] = __builtin_amdgcn_mfma_f32_16x16x32_f16(av[mt][0], bv[nt * 2 + 0], acc0[mt][nt], 0, 0, 0);
        acc1[mt][nt] = __builtin_amdgcn_mfma_f32_16x16x32_f16(av[mt][0], bv[nt * 2 + 1], acc1[mt][nt], 0, 0, 0);
        acc1[mt][nt] = __builtin_amdgcn_mfma_f32_16x16x32_f16(av[mt][1], bv[nt * 2 + 0], acc1[mt][nt], 0, 0, 0);
      }
  };

  f16x8 bv0[8], bv1[8];
  loadA(0); writeA(0);
  loadA(1);
  loadB(0, bv0);
  __syncthreads();

  for (int sp = 0; sp < 72; sp += 2) {
    if (sp + 1 < 72) { writeA(1); loadB(sp + 1, bv1); }
    if (sp + 2 < 72) loadA(sp + 2);
    mfmaStep(0, bv0);
    __syncthreads();
    if (sp + 2 < 72) { writeA(0); loadB(sp + 2, bv0); }
    if (sp + 3 < 72) loadA(sp + 3);
    mfmaStep(1, bv1);
    __syncthreads();
  }

  // epilogue
  uint32_t* hh = nullptr;
  if (EPI == 2) {
    hh = reinterpret_cast<uint32_t*>(lds);
    for (int i = tid; i < 4096; i += 256) hh[i] = 0;
    __syncthreads();
  }
#pragma unroll
  for (int mt = 0; mt < 4; mt++) {
#pragma unroll
    for (int i = 0; i < 4; i++) {
      const int pxl = wr * 64 + mt * 16 + (lane >> 4) * 4 + i;
      const int p = px0 + pxl;
      const int pr = p / PWl, pc = p - pr * PWl;
      if (!(pr >= 1 && pr <= H && pc >= 1 && pc <= W)) continue;
      const int hw = (pr - 1) * W + (pc - 1);
#pragma unroll
      for (int nt = 0; nt < 4; nt++) {
        const int oc = oc0 + wc * 64 + nt * 16 + ln15;
        const float v = acc0[mt][nt][i] + acc1[mt][nt][i] * 4.8828125e-4f;
        if (EPI == 2) {
          if (oc < NCLS) {
            float y = v + a.bias[oc];
            float pcs = 1.0f / (1.0f + expf(-y));
            float s = pcs * a.ctrp[2 * cLCUM[l] + bidx * HW + hw];
            s = (s > 0.05f) ? s : 0.f;
            a.scores[(size_t)NCLS * (2 * cLCUM[l] + bidx * HW) + (size_t)oc * HW + hw] = s;
            lds_hist_add(hh, __float_as_uint(s) >> 20);
          }
        } else {
          float y = fmaxf(v + a.bias[oc], 0.f);
          if (EPI == 0) {
            size_t o = (size_t)(PB + p) * 256 + oc;
            unsigned short h0, h1;
            split2(y, h0, h1);
            a.Y0[o] = h0; a.Y1[o] = h1;
          } else {
            a.actf[(size_t)(PB + p) * 256 + oc] = y;
          }
        }
      }
    }
  }
  if (EPI == 2) {
    __syncthreads();
    uint32_t* gh = a.hist + (size_t)(l * 2 + bidx) * 4096;
    for (int i = tid; i < 4096; i += 256) { uint32_t v = hh[i]; if (v) atomicAdd(&gh[i], v); }
  }
}

// ---------------- merged two-tower conv, 512 threads: 128px x 256oc per block ----------------
// A-tile staged once per step serves all 256 oc (halved A traffic); 8 waves = 2 px-halves x 4 oc-quarters
struct Mf2Args {
  const unsigned short *X0a, *X1a, *X0b, *X1b;
  const unsigned short *Wpa, *Wpb;
  const float *ba, *bb;
  unsigned short *Y0a, *Y1a, *Y0b, *Y1b;
  float* actf;   // LAST: tower 0 writes fp32 act here
};

template<int LAST>
__global__ __launch_bounds__(512, 4)
void conv2_mfma(Mf2Args g) {
  __shared__ __align__(16) unsigned short lds[18432];
  const int tid = threadIdx.x;
  const int lane = tid & 63;
  const int wid = tid >> 6;          // 0..7

  const int id = blockIdx.x;
  const int w = (id & 7) * 84 + (id >> 3);   // nwg=672, bijective XCD chunking
  const int bx = w >> 1;
  const int t = w & 1;
  const unsigned short* X0 = t ? g.X0b : g.X0a;
  const unsigned short* X1 = t ? g.X1b : g.X1a;
  const unsigned short* Wp = t ? g.Wpb : g.Wpa;
  const float* bias = t ? g.bb : g.ba;

  int pi = 0;
#pragma unroll
  for (int i = 1; i < 10; i++) if (bx >= cCB[i]) pi = i;
  const int l = pi >> 1;
  const int pxb = bx - cCB[pi];
  const int px0 = pxb * 128;
  const int PB = cPBASE[pi];
  const int W = cLW[l], H = cLH[l], PWl = W + 2;

  // staging: 512 threads x 2 splits: row = tid>>2 (0..127), g = tid&3
  const int srow = tid >> 2;
  const int sg = tid & 3;

  const int wr = wid >> 2, wc = wid & 3;   // px half, oc quarter
  const int kg = lane >> 4, ln15 = lane & 15;
  int fA[4];
#pragma unroll
  for (int mt = 0; mt < 4; mt++) fA[mt] = (wr * 64 + mt * 16 + ln15) * 72 + kg * 8;
  const int ocfb = wc * 4;

  f32x4 acc0[4][4], acc1[4][4];
#pragma unroll
  for (int mt = 0; mt < 4; mt++)
#pragma unroll
    for (int nt = 0; nt < 4; nt++) {
      acc0[mt][nt] = (f32x4){0.f, 0.f, 0.f, 0.f};
      acc1[mt][nt] = (f32x4){0.f, 0.f, 0.f, 0.f};
    }

  s16x8 ra[2];
  auto loadA = [&](int step) {
    const int rr = step >> 3;
    const int c0 = (step & 7) << 5;
    const int dh = rr / 3 - 1, dw = rr - (rr / 3) * 3 - 1;
    const long long OFF = (long long)(PB + px0 + dh * PWl + dw);
    ra[0] = *reinterpret_cast<const s16x8*>(X0 + (OFF + srow) * 256 + c0 + sg * 8);
    ra[1] = *reinterpret_cast<const s16x8*>(X1 + (OFF + srow) * 256 + c0 + sg * 8);
  };
  auto writeA = [&](int buf) {
#pragma unroll
    for (int s = 0; s < 2; s++) {
      const int o = buf * 9216 + srow * 72 + (s * 4 + sg) * 8;
      *reinterpret_cast<s16x8*>(&lds[o]) = ra[s];
    }
  };
  auto loadB = [&](int step, f16x8* bv) {
    const int rr = step >> 3, cc = step & 7;
#pragma unroll
    for (int nt = 0; nt < 4; nt++) {
      const size_t bo = ((size_t)((rr * 2) * 16 + ocfb + nt) * 8 + cc) * 512 + lane * 8;
      bv[nt * 2 + 0] = *reinterpret_cast<const f16x8*>(Wp + bo);
      bv[nt * 2 + 1] = *reinterpret_cast<const f16x8*>(Wp + bo + 65536);
    }
  };
  auto mfmaStep = [&](int buf, const f16x8* bv) {
    f16x8 av[4][2];
#pragma unroll
    for (int mt = 0; mt < 4; mt++) {
      av[mt][0] = *reinterpret_cast<const f16x8*>(&lds[buf * 9216 + fA[mt]]);
      av[mt][1] = *reinterpret_cast<const f16x8*>(&lds[buf * 9216 + fA[mt] + 32]);
    }
#pragma unroll
    for (int mt = 0; mt < 4; mt++)
#pragma unroll
      for (int nt = 0; nt < 4; nt++) {
        acc0[mt][nt] = __builtin_amdgcn_mfma_f32_16x16x32_f16(av[mt][0], bv[nt * 2 + 0], acc0[mt][nt], 0, 0, 0);
        acc1[mt][nt] = __builtin_amdgcn_mfma_f32_16x16x32_f16(av[mt][0], bv[nt * 2 + 1], acc1[mt][nt], 0, 0, 0);
        acc1[mt][nt] = __builtin_amdgcn_mfma_f32_16x16x32_f16(av[mt][1], bv[nt * 2 + 0], acc1[mt][nt], 0, 0, 0);
      }
  };

  f16x8 bv0[8], bv1[8];
  loadA(0); writeA(0);
  loadA(1);
  loadB(0, bv0);
  __syncthreads();

  for (int sp = 0; sp < 72; sp += 2) {
    if (sp + 1 < 72) { writeA(1); loadB(sp + 1, bv1); }
    if (sp + 2 < 72) loadA(sp + 2);
    mfmaStep(0, bv0);
    __syncthreads();
    if (sp + 2 < 72) { writeA(0); loadB(sp + 2, bv0); }
    if (sp + 3 < 72) loadA(sp + 3);
    mfmaStep(1, bv1);
    __syncthreads();
  }

  // epilogue: relu+bias; tower0@LAST -> fp32 act, else fp16 split pair
  unsigned short* Y0 = t ? g.Y0b : g.Y0a;
  unsigned short* Y1 = t ? g.Y1b : g.Y1a;
#pragma unroll
  for (int mt = 0; mt < 4; mt++) {
#pragma unroll
    for (int i = 0; i < 4; i++) {
      const int pxl = wr * 64 + mt * 16 + (lane >> 4) * 4 + i;
      const int p = px0 + pxl;
      const int pr = p / PWl, pc = p - pr * PWl;
      if (!(pr >= 1 && pr <= H && pc >= 1 && pc <= W)) continue;
#pragma unroll
      for (int nt = 0; nt < 4; nt++) {
        const int oc = wc * 64 + nt * 16 + ln15;
        const float v = acc0[mt][nt][i] + acc1[mt][nt][i] * 4.8828125e-4f;
        float y = fmaxf(v + bias[oc], 0.f);
        if (LAST && t == 0) {
          g.actf[(size_t)(PB + p) * 256 + oc] = y;
        } else {
          size_t o = (size_t)(PB + p) * 256 + oc;
          unsigned short h0, h1;
          split2(y, h0, h1);
          Y0[o] = h0; Y1[o] = h1;
        }
      }
    }
  }
}

// ---------------- ctr + reg head: wave-per-px over px-major fp32 act ----------------
__global__ __launch_bounds__(256)
void k_head2(const float* __restrict__ headact, const float* __restrict__ wh,
             const float* __restrict__ ctb, const float* __restrict__ pdb,
             const float* __restrict__ scl,
             float* __restrict__ ctrp, float* __restrict__ regb) {
  __shared__ float swh[11520];
  for (int i = threadIdx.x; i < 11520; i += 256) swh[i] = wh[i];
  int bx = blockIdx.x; int l = 0;
#pragma unroll
  for (int i = 1; i < 5; i++) if (bx >= cCPX64[i]) l = i;
  const int lblk = bx - cCPX64[l];
  const int H = cLH[l], W = cLW[l], HW = cLHW[l]; const int N = 2 * HW;
  const int lane = threadIdx.x & 63;
  const int wv = threadIdx.x >> 6;
  __syncthreads();
  const float bb0 = ctb[0], bb1 = pdb[0], bb2 = pdb[1], bb3 = pdb[2], bb4 = pdb[3];
  const float sc = scl[l];
  const int c4 = lane * 4;
  for (int t = 0; t < 16; ++t) {
    int px = lblk * 64 + wv * 16 + t;
    if (px >= N) break;
    int bb = px / HW; int hw = px - bb * HW; int hh = hw / W; int ww = hw - hh * W;
    const int PB = cPBASE[l * 2 + bb];
    float a0 = 0.f, a1 = 0.f, a2 = 0.f, a3 = 0.f, a4 = 0.f;
#pragma unroll
    for (int r = 0; r < 9; r++) {
      int dh = r / 3 - 1, dw = r % 3 - 1;
      int ih = hh + dh, iw = ww + dw;
      if (!(((unsigned)ih < (unsigned)H) && ((unsigned)iw < (unsigned)W))) continue;
      const float4 x = *reinterpret_cast<const float4*>(
          headact + (size_t)(PB + (ih + 1) * (W + 2) + (iw + 1)) * 256 + c4);
      const float* wr = &swh[(size_t)(r * 256 + c4) * 5];
      a0 = fmaf(x.x, wr[0],  a0); a1 = fmaf(x.x, wr[1],  a1); a2 = fmaf(x.x, wr[2],  a2);
      a3 = fmaf(x.x, wr[3],  a3); a4 = fmaf(x.x, wr[4],  a4);
      a0 = fmaf(x.y, wr[5],  a0); a1 = fmaf(x.y, wr[6],  a1); a2 = fmaf(x.y, wr[7],  a2);
      a3 = fmaf(x.y, wr[8],  a3); a4 = fmaf(x.y, wr[9],  a4);
      a0 = fmaf(x.z, wr[10], a0); a1 = fmaf(x.z, wr[11], a1); a2 = fmaf(x.z, wr[12], a2);
      a3 = fmaf(x.z, wr[13], a3); a4 = fmaf(x.z, wr[14], a4);
      a0 = fmaf(x.w, wr[15], a0); a1 = fmaf(x.w, wr[16], a1); a2 = fmaf(x.w, wr[17], a2);
      a3 = fmaf(x.w, wr[18], a3); a4 = fmaf(x.w, wr[19], a4);
    }
#pragma unroll
    for (int off = 32; off > 0; off >>= 1) {
      a0 += __shfl_xor(a0, off, 64); a1 += __shfl_xor(a1, off, 64); a2 += __shfl_xor(a2, off, 64);
      a3 += __shfl_xor(a3, off, 64); a4 += __shfl_xor(a4, off, 64);
    }
    if (lane == 0) {
      const int gi = 2 * cLCUM[l] + bb * HW + hw;
      ctrp[gi] = 1.0f / (1.0f + expf(-(a0 + bb0)));
      float* rg = regb + (size_t)gi * 4;
      rg[0] = fmaxf((a1 + bb1) * sc, 0.f);
      rg[1] = fmaxf((a2 + bb2) * sc, 0.f);
      rg[2] = fmaxf((a3 + bb3) * sc, 0.f);
      rg[3] = fmaxf((a4 + bb4) * sc, 0.f);
    }
  }
}

// ---------------- top-k pipeline ----------------
__global__ void k_init(uint32_t* __restrict__ hist, uint32_t* __restrict__ ctrA,
                       uint32_t* __restrict__ ctrB, uint32_t* __restrict__ survCnt) {
  int i = blockIdx.x * blockDim.x + threadIdx.x;
  if (i < 40960) hist[i] = 0;
  if (i < 10) { ctrA[i] = 0; ctrB[i] = 0; }
  if (i < 2) survCnt[i] = 0;
}

__global__ __launch_bounds__(256)
void k_select(const uint32_t* __restrict__ hist, int* __restrict__ meta) {
  const int sid = blockIdx.x;
  const uint32_t* gh = hist + (size_t)sid * 4096;
  __shared__ uint32_t ps[256];
  uint32_t sum = 0;
  for (int i = 0; i < 16; i++) sum += gh[threadIdx.x * 16 + i];
  ps[threadIdx.x] = sum;
  __syncthreads();
  if (threadIdx.x == 0) {
    uint32_t c = 0; int T = 0, m = 1000;
    for (int ch = 255; ch >= 0; --ch) {
      if (c + ps[ch] >= 1000u) {
        for (int t = ch * 16 + 15; t >= ch * 16; --t) {
          uint32_t hv = gh[t];
          if (c + hv >= 1000u) { T = t; m = (int)(1000u - c); break; }
          c += hv;
        }
        break;
      }
      c += ps[ch];
    }
    meta[sid * 4 + 0] = T;
    meta[sid * 4 + 1] = (int)c;
    meta[sid * 4 + 2] = m;
    meta[sid * 4 + 3] = (int)gh[T];
  }
}

// two-pass block-aggregated collect: 2 global atomics per block
__global__ __launch_bounds__(256)
void k_collect(const float* __restrict__ scores, const int* __restrict__ meta,
               unsigned long long* __restrict__ listA, unsigned long long* __restrict__ listB,
               uint32_t* __restrict__ ctrA, uint32_t* __restrict__ ctrB) {
  const int sid = blockIdx.y; const int l = sid >> 1, b = sid & 1;
  const int HW = cLHW[l]; const int size = NCLS * HW;
  const int base = blockIdx.x * 4096;
  if (base >= size) return;
  const size_t sbase = (size_t)NCLS * (2 * cLCUM[l] + b * HW);
  const float* sb = scores + sbase;
  unsigned long long* lB = listB + sbase;
  unsigned long long* lA = listA + (size_t)sid * 1024;
  const uint32_t T = (uint32_t)meta[sid * 4];
  const int lane = (int)(threadIdx.x & 63u);
  __shared__ uint32_t cA, cB, bA, bB;
  if (threadIdx.x == 0) { cA = 0; cB = 0; }
  __syncthreads();
  uint32_t wa = 0, wb = 0;
  for (int j = 0; j < 16; j++) {
    int i = base + threadIdx.x + j * 256;
    bool inb = (i < size);
    uint32_t bits = inb ? __float_as_uint(sb[i]) : 0u;
    uint32_t bkt = bits >> 20;
    unsigned long long mA = __ballot(inb && bkt > T);
    unsigned long long mB = __ballot(inb && bkt == T);
    if (lane == 0) { wa += (uint32_t)__popcll(mA); wb += (uint32_t)__popcll(mB); }
  }
  if (lane == 0) { if (wa) atomicAdd(&cA, wa); if (wb) atomicAdd(&cB, wb); }
  __syncthreads();
  if (threadIdx.x == 0) {
    bA = cA ? atomicAdd(&ctrA[sid], cA) : 0u;
    bB = cB ? atomicAdd(&ctrB[sid], cB) : 0u;
    cA = 0; cB = 0;
  }
  __syncthreads();
  for (int j = 0; j < 16; j++) {
    int i = base + threadIdx.x + j * 256;
    bool inb = (i < size);
    uint32_t bits = inb ? __float_as_uint(sb[i]) : 0u;
    uint32_t bkt = bits >> 20;
    bool pA = inb && bkt > T;
    bool pB = inb && bkt == T;
    unsigned long long key = 0;
    if (pA || pB) {
      int cls = i / HW; int hw = i - cls * HW;
      uint32_t idx = (uint32_t)(hw * NCLS + cls);
      key = ((unsigned long long)bits << 32) | (unsigned long long)(0xFFFFFFFFu - idx);
    }
    unsigned long long mA = __ballot(pA);
    unsigned long long mB = __ballot(pB);
    unsigned long long lt = (1ull << lane) - 1ull;
    if (mA) {
      int ld = __ffsll(mA) - 1;
      uint32_t wbs = 0;
      if (lane == ld) wbs = atomicAdd(&cA, (uint32_t)__popcll(mA));
      wbs = (uint32_t)__shfl((int)wbs, ld, 64);
      if (pA) {
        uint32_t pos = bA + wbs + (uint32_t)__popcll(mA & lt);
        if (pos < 1024u) lA[pos] = key;
      }
    }
    if (mB) {
      int ld = __ffsll(mB) - 1;
      uint32_t wbs = 0;
      if (lane == ld) wbs = atomicAdd(&cB, (uint32_t)__popcll(mB));
      wbs = (uint32_t)__shfl((int)wbs, ld, 64);
      if (pB) lB[bB + wbs + (uint32_t)__popcll(mB & lt)] = key;
    }
  }
}

__global__ __launch_bounds__(1024)
void k_refine(const int* __restrict__ meta, const unsigned long long* __restrict__ listB,
              unsigned long long* __restrict__ listA, uint32_t* __restrict__ ctrA) {
  const int sid = blockIdx.x; const int l = sid >> 1, b = sid & 1;
  const int HW = cLHW[l];
  const size_t sbase = (size_t)NCLS * (2 * cLCUM[l] + b * HW);
  const unsigned long long* lB = listB + sbase;
  const int nB = meta[sid * 4 + 3];
  int m = meta[sid * 4 + 2];
  __shared__ uint32_t h[256];
  __shared__ unsigned long long sPre;
  __shared__ int sM;
  __shared__ uint32_t sCnt;
  unsigned long long prefix = 0, mask = 0;
  for (int p = 7; p >= 0; --p) {
    for (int i = threadIdx.x; i < 256; i += 1024) h[i] = 0;
    __syncthreads();
    for (int i = threadIdx.x; i < nB; i += 1024) {
      unsigned long long k = lB[i];
      if ((k & mask) == prefix) {
        uint32_t bkt = (uint32_t)((k >> (p * 8)) & 255ull);
        lds_hist_add(h, bkt);
      }
    }
    __syncthreads();
    if (threadIdx.x == 0) {
      uint32_t c = 0; int sel = 0; int mnew = m;
      for (int t = 255; t >= 0; --t) {
        if (c + h[t] >= (uint32_t)m) { sel = t; mnew = m - (int)c; break; }
        c += h[t];
      }
      sPre = prefix | ((unsigned long long)sel << (p * 8));
      sM = mnew;
    }
    __syncthreads();
    prefix = sPre; m = sM;
    mask |= (0xFFull << (p * 8));
    __syncthreads();
  }
  if (threadIdx.x == 0) sCnt = ctrA[sid];
  __syncthreads();
  for (int i = threadIdx.x; i < nB; i += 1024) {
    unsigned long long k = lB[i];
    if (k >= prefix) {
      uint32_t pos = atomicAdd(&sCnt, 1u);
      if (pos < 1024u) listA[(size_t)sid * 1024 + pos] = k;
    }
  }
  __syncthreads();
  if (threadIdx.x == 0) ctrA[sid] = sCnt;
}

__global__ __launch_bounds__(256)
void k_sortdec(const unsigned long long* __restrict__ listA, const uint32_t* __restrict__ ctrA,
               const float* __restrict__ regb, float* __restrict__ cbox,
               float* __restrict__ cscr, float* __restrict__ ccls) {
  const int sid = blockIdx.x; const int l = sid >> 1, b = sid & 1;
  const int HW = cLHW[l], W = cLW[l];
  __shared__ unsigned long long key[1024];
  int n = (int)ctrA[sid]; if (n > 1024) n = 1024;
  for (int i = threadIdx.x; i < 1024; i += 256)
    key[i] = (i < n) ? listA[(size_t)sid * 1024 + i] : 0ull;
  __syncthreads();
  for (int len = 2; len <= 1024; len <<= 1) {
    for (int j = len >> 1; j > 0; j >>= 1) {
      for (int t = threadIdx.x; t < 512; t += 256) {
        int i = ((t & ~(j - 1)) << 1) | (t & (j - 1));
        int pp = i | j;
        unsigned long long a = key[i], bq = key[pp];
        bool desc = ((i & len) == 0);
        if ((a < bq) == desc) { key[i] = bq; key[pp] = a; }
      }
      __syncthreads();
    }
  }
  for (int r = threadIdx.x; r < 1000; r += 256) {
    unsigned long long k = key[r];
    uint32_t bits = (uint32_t)(k >> 32);
    uint32_t idx = 0xFFFFFFFFu - (uint32_t)(k & 0xFFFFFFFFull);
    float val = __uint_as_float(bits);
    float sc = sqrtf(fmaxf(val, 1e-12f));
    int cls = (int)(idx % NCLS); int loc = (int)(idx / NCLS);
    int hh = loc / W; int ww = loc - hh * W;
    float cx = (float)(ww * cLSTR[l] + (cLSTR[l] >> 1));
    float cy = (float)(hh * cLSTR[l] + (cLSTR[l] >> 1));
    const float* rg = regb + (size_t)(2 * cLCUM[l] + b * HW + loc) * 4;
    int slot = b * 5000 + l * 1000 + r;
    cbox[slot * 4 + 0] = cx - rg[0];
    cbox[slot * 4 + 1] = cy - rg[1];
    cbox[slot * 4 + 2] = cx + rg[2];
    cbox[slot * 4 + 3] = cy + rg[3];
    cscr[slot] = sc;
    ccls[slot] = (float)cls;
  }
}

// ---------------- NMS stage A: per-(class,batch) greedy NMS, capped at 100 ----------------
#define NMSC 1536
__global__ __launch_bounds__(256)
void k_nmscls(const float* __restrict__ cbox, const float* __restrict__ cscr,
              const float* __restrict__ ccls,
              unsigned long long* __restrict__ surv, uint32_t* __restrict__ survCnt) {
  const int cls = blockIdx.x;
  const int b = blockIdx.y;
  __shared__ unsigned short mslot[5024];
  __shared__ float ms[5024];
  __shared__ float kx1[NMSC], ky1[NMSC], kx2[NMSC], ky2[NMSC], kar[NMSC];
  __shared__ uint32_t mcnt;
  __shared__ int sPick; __shared__ float sPickV;
  __shared__ float pb[5];
  __shared__ float wvv[4]; __shared__ int wvi[4];
  if (threadIdx.x == 0) mcnt = 0;
  __syncthreads();
  const float fc = (float)cls;
  for (int j = threadIdx.x; j < 5000; j += 256) {
    if (ccls[b * 5000 + j] == fc) {
      uint32_t p = atomicAdd(&mcnt, 1u);
      mslot[p] = (unsigned short)j;
      ms[p] = cscr[b * 5000 + j];
    }
  }
  __syncthreads();
  const int n = (int)mcnt;
  if (n == 0) return;
  const float off = fc * 10000.0f;
  const int nc = n < NMSC ? n : NMSC;
  for (int i = threadIdx.x; i < nc; i += 256) {
    const float4 bq = *reinterpret_cast<const float4*>(cbox + ((size_t)b * 5000 + mslot[i]) * 4);
    float x1 = bq.x + off, y1 = bq.y + off, x2 = bq.z + off, y2 = bq.w + off;
    kx1[i] = x1; ky1[i] = y1; kx2[i] = x2; ky2[i] = y2; kar[i] = (x2 - x1) * (y2 - y1);
  }
  __syncthreads();
  const int lane = threadIdx.x & 63, wv = threadIdx.x >> 6;
  for (int it = 0; it < 100; ++it) {
    float best = -1.f; int bi = 0x7FFF; int bidx = 0;
    for (int i = threadIdx.x; i < n; i += 256) {
      float v = ms[i];
      int sl = mslot[i];
      if (v > best || (v == best && sl < bi)) { best = v; bi = sl; bidx = i; }
    }
    for (int o = 32; o > 0; o >>= 1) {
      float ov = __shfl_down(best, o, 64);
      int oi = __shfl_down(bi, o, 64);
      int ox = __shfl_down(bidx, o, 64);
      if (ov > best || (ov == best && oi < bi)) { best = ov; bi = oi; bidx = ox; }
    }
    if (lane == 0) { wvv[wv] = best; wvi[wv] = (bidx << 13) | bi; }
    __syncthreads();
    if (threadIdx.x == 0) {
      float bb = wvv[0]; int pk = wvi[0];
      for (int q = 1; q < 4; q++) {
        float v = wvv[q]; int c = wvi[q];
        if (v > bb || (v == bb && (c & 8191) < (pk & 8191))) { bb = v; pk = c; }
      }
      sPickV = bb; sPick = pk;
      if (bb >= 0.f) {
        int slot = pk & 8191;
        uint32_t bits = __float_as_uint(bb);
        uint32_t gslot = (uint32_t)(b * 5000 + slot);
        unsigned long long key = ((unsigned long long)bits << 32) |
                                 (unsigned long long)(0xFFFFFFFFu - gslot);
        uint32_t pos = atomicAdd(&survCnt[b], 1u);
        surv[(size_t)b * 5000 + pos] = key;
        const float4 bx = *reinterpret_cast<const float4*>(cbox + (size_t)gslot * 4);
        pb[0] = bx.x + off; pb[1] = bx.y + off; pb[2] = bx.z + off; pb[3] = bx.w + off;
        pb[4] = (pb[2] - pb[0]) * (pb[3] - pb[1]);
      }
    }
    __syncthreads();
    if (sPickV < 0.f) break;
    const int pidx = sPick >> 13;
    const float bx1 = pb[0], by1 = pb[1], bx2 = pb[2], by2 = pb[3], ba = pb[4];
    for (int i = threadIdx.x; i < n; i += 256) {
      float v = ms[i];
      if (v < 0.f) continue;
      float x1, y1, x2, y2, ar;
      if (i < NMSC) {
        x1 = kx1[i]; y1 = ky1[i]; x2 = kx2[i]; y2 = ky2[i]; ar = kar[i];
      } else {
        const float4 bq = *reinterpret_cast<const float4*>(cbox + ((size_t)b * 5000 + mslot[i]) * 4);
        x1 = bq.x + off; y1 = bq.y + off; x2 = bq.z + off; y2 = bq.w + off;
        ar = (x2 - x1) * (y2 - y1);
      }
      float ix1 = fmaxf(bx1, x1), iy1 = fmaxf(by1, y1);
      float ix2 = fminf(bx2, x2), iy2 = fminf(by2, y2);
      float iw = fmaxf(ix2 - ix1, 0.f), ih = fmaxf(iy2 - iy1, 0.f);
      float inter = iw * ih;
      float iou = inter / ((ba + ar - inter) + 1e-9f);
      if (iou > 0.6f || i == pidx) ms[i] = -1.0f;
    }
    __syncthreads();
  }
}

// ---------------- NMS stage B: top-100 survivors by key, write rows ----------------
__global__ __launch_bounds__(1024)
void k_nmsfinal(const unsigned long long* __restrict__ surv, const uint32_t* __restrict__ survCnt,
                const float* __restrict__ cbox, const float* __restrict__ ccls,
                float* __restrict__ out) {
  const int b = blockIdx.x;
  const int n = (int)survCnt[b];
  const unsigned long long* sv = surv + (size_t)b * 5000;
  const int m = n < 100 ? n : 100;
  __shared__ uint32_t h[256];
  __shared__ unsigned long long sPre; __shared__ int sM;
  __shared__ unsigned long long topk[128];
  __shared__ uint32_t tcnt;
  unsigned long long prefix = 0, mask = 0;
  int mm = m;
  if (m > 0) {
    for (int p = 7; p >= 0; --p) {
      for (int i = threadIdx.x; i < 256; i += 1024) h[i] = 0;
      __syncthreads();
      for (int i = threadIdx.x; i < n; i += 1024) {
        unsigned long long k = sv[i];
        if ((k & mask) == prefix) lds_hist_add(h, (uint32_t)((k >> (p * 8)) & 255ull));
      }
      __syncthreads();
      if (threadIdx.x == 0) {
        uint32_t c = 0; int sel = 0; int mnew = mm;
        for (int t = 255; t >= 0; --t) {
          if (c + h[t] >= (uint32_t)mm) { sel = t; mnew = mm - (int)c; break; }
          c += h[t];
        }
        sPre = prefix | ((unsigned long long)sel << (p * 8));
        sM = mnew;
      }
      __syncthreads();
      prefix = sPre; mm = sM;
      mask |= (0xFFull << (p * 8));
      __syncthreads();
    }
  }
  if (threadIdx.x == 0) tcnt = 0;
  for (int i = threadIdx.x; i < 128; i += 1024) topk[i] = 0;
  __syncthreads();
  if (m > 0) {
    for (int i = threadIdx.x; i < n; i += 1024) {
      unsigned long long k = sv[i];
      if (k >= prefix) {
        uint32_t p = atomicAdd(&tcnt, 1u);
        if (p < 128) topk[p] = k;
      }
    }
  }
  __syncthreads();
  for (int len = 2; len <= 128; len <<= 1) {
    for (int j = len >> 1; j > 0; j >>= 1) {
      for (int t = threadIdx.x; t < 64; t += 1024) {
        int i = ((t & ~(j - 1)) << 1) | (t & (j - 1));
        int pp = i | j;
        unsigned long long a = topk[i], bq = topk[pp];
        bool desc = ((i & len) == 0);
        if ((a < bq) == desc) { topk[i] = bq; topk[pp] = a; }
      }
      __syncthreads();
    }
  }
  if (threadIdx.x < 100) {
    int it = threadIdx.x;
    float* orow = out + ((size_t)b * 100 + it) * 6;
    if (it < m) {
      unsigned long long k = topk[it];
      uint32_t gslot = 0xFFFFFFFFu - (uint32_t)(k & 0xFFFFFFFFull);
      const float4 bx = *reinterpret_cast<const float4*>(cbox + (size_t)gslot * 4);
      orow[0] = bx.x; orow[1] = bx.y; orow[2] = bx.z; orow[3] = bx.w;
      orow[4] = __uint_as_float((uint32_t)(k >> 32));
      orow[5] = ccls[gslot];
    } else {
      orow[0] = 0.f; orow[1] = 0.f; orow[2] = 0.f;
      orow[3] = 0.f; orow[4] = 0.f; orow[5] = 0.f;
    }
  }
}

// ---------------- host launch ----------------
static inline size_t alignup(size_t x) { return (x + 255) & ~(size_t)255; }

extern "C" void kernel_launch(void* const* d_in, const int* in_sizes, int n_in,
                              void* d_out, int out_size, void* d_ws, size_t ws_size,
                              hipStream_t stream) {
  (void)in_sizes; (void)n_in; (void)out_size;
  const float* p0 = (const float*)d_in[0];
  const float* p1 = (const float*)d_in[1];
  const float* p2 = (const float*)d_in[2];
  const float* p3 = (const float*)d_in[3];
  const float* p4 = (const float*)d_in[4];
  const float* cls_w   = (const float*)d_in[5];
  const float* cls_b   = (const float*)d_in[6];
  const float* box_w   = (const float*)d_in[7];
  const float* box_b   = (const float*)d_in[8];
  const float* logit_w = (const float*)d_in[9];
  const float* logit_b = (const float*)d_in[10];
  const float* pred_w  = (const float*)d_in[11];
  const float* pred_b  = (const float*)d_in[12];
  const float* ctr_w   = (const float*)d_in[13];
  const float* ctr_b   = (const float*)d_in[14];
  const float* scales  = (const float*)d_in[15];

  char* base = (char*)d_ws;
  size_t off = 0;
  auto take = [&](size_t bytes) { void* p = base + off; off = alignup(off + bytes); return p; };
  float* regb = (float*)take((size_t)4 * 2 * TOTHW * 4);
  float* ctrp = (float*)take((size_t)2 * TOTHW * 4);
  uint32_t* hist = (uint32_t*)take((size_t)40960 * 4);
  int* meta = (int*)take((size_t)40 * 4);
  uint32_t* ctrA = (uint32_t*)take(256);
  uint32_t* ctrB = (uint32_t*)take(256);
  uint32_t* survCnt = (uint32_t*)take(256);
  unsigned long long* listA = (unsigned long long*)take((size_t)10 * 1024 * 8);
  unsigned long long* surv = (unsigned long long*)take((size_t)2 * 5000 * 8);
  float* cbox = (float*)take((size_t)2 * 5000 * 16);
  float* cscr = (float*)take((size_t)2 * 5000 * 4);
  float* ccls = (float*)take((size_t)2 * 5000 * 4);
  float* wh   = (float*)take((size_t)9 * 256 * 5 * 4);
  unsigned short* wpackF = (unsigned short*)take((size_t)9 * WLAYER * 2);
  unsigned short* P_0 = (unsigned short*)take(SBE * 2);   // pair A
  unsigned short* P_1 = (unsigned short*)take(SBE * 2);
  unsigned short* R1_0 = (unsigned short*)take(SBE * 2);  // pair B
  unsigned short* R1_1 = (unsigned short*)take(SBE * 2);
  unsigned short* R2_0 = (unsigned short*)take(SBE * 2);  // pair C
  unsigned short* R2_1 = (unsigned short*)take(SBE * 2);
  (void)take(65536);                                 // halo-read safety pad
  unsigned short* D_0 = (unsigned short*)take(SBE * 2);   // pair D (merged mode only)
  unsigned short* D_1 = (unsigned short*)take(SBE * 2);
  (void)take(65536);                                 // halo pad after D
  const bool merged = (ws_size >= off);              // constant across calls -> graph-safe

  float* scores = (float*)R1_0;                      // B region free when logits runs
  unsigned long long* listB = (unsigned long long*)R2_0;  // C region free at collect

  hipLaunchKernelGGL(k_init, dim3(160), dim3(256), 0, stream, hist, ctrA, ctrB, survCnt);
  hipLaunchKernelGGL(k_packhead, dim3(9), dim3(256), 0, stream, ctr_w, pred_w, wh);
  hipLaunchKernelGGL(k_packall, dim3(256, 9), dim3(256), 0, stream, box_w, cls_w, logit_w, wpackF);
  hipLaunchKernelGGL(k_zero, dim3(168), dim3(256), 0, stream, P_0, P_1);
  hipLaunchKernelGGL(k_zero, dim3(168), dim3(256), 0, stream, R1_0, R1_1);
  hipLaunchKernelGGL(k_zero, dim3(168), dim3(256), 0, stream, R2_0, R2_1);
  if (merged) hipLaunchKernelGGL(k_zero, dim3(168), dim3(256), 0, stream, D_0, D_1);
  hipLaunchKernelGGL(k_prep, dim3(390), dim3(256), 0, stream, p0, p1, p2, p3, p4, P_0, P_1);

  auto runConv = [&](int epi, int layer, const unsigned short* x0, const unsigned short* x1,
                     const float* bias, unsigned short* y0, unsigned short* y1,
                     float* af, float* sc) {
    MfArgs a;
    a.X0 = x0; a.X1 = x1; a.Wp = wpackF + (size_t)layer * WLAYER; a.bias = bias;
    a.Y0 = y0; a.Y1 = y1; a.actf = af; a.scores = sc; a.ctrp = ctrp;
    a.hist = hist;
    if (epi == 0)      hipLaunchKernelGGL(conv_mfma<0>, dim3(672), dim3(256), 0, stream, a);
    else if (epi == 1) hipLaunchKernelGGL(conv_mfma<1>, dim3(672), dim3(256), 0, stream, a);
    else               hipLaunchKernelGGL(conv_mfma<2>, dim3(336), dim3(256), 0, stream, a);
  };

  if (merged) {
    // both towers per dispatch, 512-thr blocks (128px x 256oc): A=P, B=R1, C=R2, D
    auto run2 = [&](int last, int layer,
                    const unsigned short* xa0, const unsigned short* xa1,
                    const unsigned short* xb0, const unsigned short* xb1,
                    unsigned short* ya0, unsigned short* ya1,
                    unsigned short* yb0, unsigned short* yb1, float* af) {
      Mf2Args g;
      g.X0a = xa0; g.X1a = xa1; g.X0b = xb0; g.X1b = xb1;
      g.Wpa = wpackF + (size_t)layer * WLAYER;
      g.Wpb = wpackF + (size_t)(4 + layer) * WLAYER;
      g.ba = box_b + layer * 256; g.bb = cls_b + layer * 256;
      g.Y0a = ya0; g.Y1a = ya1; g.Y0b = yb0; g.Y1b = yb1; g.actf = af;
      if (last) hipLaunchKernelGGL(conv2_mfma<1>, dim3(672), dim3(512), 0, stream, g);
      else      hipLaunchKernelGGL(conv2_mfma<0>, dim3(672), dim3(512), 0, stream, g);
    };
    // L0: box A->B, cls A->C
    run2(0, 0, P_0, P_1, P_0, P_1, R1_0, R1_1, R2_0, R2_1, nullptr);
    // L1: box B->D, cls C->A
    run2(0, 1, R1_0, R1_1, R2_0, R2_1, D_0, D_1, P_0, P_1, nullptr);
    // L2: box D->B, cls A->C
    run2(0, 2, D_0, D_1, P_0, P_1, R1_0, R1_1, R2_0, R2_1, nullptr);
    // L3: box B->headact(D fp32), cls C->A
    run2(1, 3, R1_0, R1_1, R2_0, R2_1, nullptr, nullptr, P_0, P_1, (float*)D_0);
    hipLaunchKernelGGL(k_head2, dim3(NPXB64), dim3(256), 0, stream, (const float*)D_0, wh,
                       ctr_b, pred_b, scales, ctrp, regb);
    // logits: reads A (cls final act), writes scores (B region)
    runConv(2, 8, P_0, P_1, logit_b, nullptr, nullptr, nullptr, scores);
  } else {
    float* headact = (float*)R2_0;   // spans R2 pair exactly
    // ---- box tower: P -> R1 -> R2 -> R1 -> headact(R2 region, fp32) ----
    runConv(0, 0, P_0,  P_1,  box_b + 0,   R1_0, R1_1, nullptr, nullptr);
    runConv(0, 1, R1_0, R1_1, box_b + 256, R2_0, R2_1, nullptr, nullptr);
    runConv(0, 2, R2_0, R2_1, box_b + 512, R1_0, R1_1, nullptr, nullptr);
    runConv(1, 3, R1_0, R1_1, box_b + 768, nullptr, nullptr, headact, nullptr);
    hipLaunchKernelGGL(k_head2, dim3(NPXB64), dim3(256), 0, stream, headact, wh, ctr_b,
                       pred_b, scales, ctrp, regb);
    hipLaunchKernelGGL(k_zero, dim3(168), dim3(256), 0, stream, R2_0, R2_1);
    // ---- cls tower: P -> R1 -> R2 -> R1 -> R2 -> scores(R1 region) ----
    runConv(0, 4, P_0,  P_1,  cls_b + 0,   R1_0, R1_1, nullptr, nullptr);
    runConv(0, 5, R1_0, R1_1, cls_b + 256, R2_0, R2_1, nullptr, nullptr);
    runConv(0, 6, R2_0, R2_1, cls_b + 512, R1_0, R1_1, nullptr, nullptr);
    runConv(0, 7, R1_0, R1_1, cls_b + 768, R2_0, R2_1, nullptr, nullptr);
    runConv(2, 8, R2_0, R2_1, logit_b, nullptr, nullptr, nullptr, scores);
  }

  // ---- top-k + decode + NMS ----
  hipLaunchKernelGGL(k_select,  dim3(10), dim3(256), 0, stream, hist, meta);
  hipLaunchKernelGGL(k_collect, dim3(297, 10), dim3(256), 0, stream, scores, meta, listA, listB, ctrA, ctrB);
  hipLaunchKernelGGL(k_refine,  dim3(10), dim3(1024), 0, stream, meta, listB, listA, ctrA);
  hipLaunchKernelGGL(k_sortdec, dim3(10), dim3(256), 0, stream, listA, ctrA, regb, cbox, cscr, ccls);
  hipLaunchKernelGGL(k_nmscls,  dim3(NCLS, 2), dim3(256), 0, stream, cbox, cscr, ccls, surv, survCnt);
  hipLaunchKernelGGL(k_nmsfinal, dim3(2), dim3(1024), 0, stream, surv, survCnt, cbox, ccls, (float*)d_out);
}

// Round 12
// 1929.468 us; speedup vs baseline: 7.7449x; 7.7449x over previous
//
#include <hip/hip_runtime.h>
#include <stdint.h>
#include <math.h>

#define NCLS 80
#define TOTHW 20267
#define WLAYER 1179648ull  // shorts per packed layer: 18*16*8*64*8

typedef _Float16 f16x8 __attribute__((ext_vector_type(8)));
typedef float f32x4 __attribute__((ext_vector_type(4)));
typedef short s16x8 __attribute__((ext_vector_type(8)));

static constexpr int cLW[5]    = {152,76,38,19,10};
static constexpr int cLH[5]    = {100,50,25,13,7};
static constexpr int cLHW[5]   = {15200,3800,950,247,70};
static constexpr int cLCUM[5]  = {0,15200,19000,19950,20197};
static constexpr int cLSTR[5]  = {8,16,32,64,128};
static constexpr int cCB[11]   = {0,123,246,278,310,319,328,331,334,335,336};
static constexpr int cPBASE[11]= {0,15744,31488,35584,39680,40832,41984,42368,42752,42880,43008};
static constexpr int cRCUM[11] = {0,100,200,250,300,325,350,363,376,383,390};
static constexpr int cCPX64[6] = {0,475,594,624,632,635};
#define NPXB64 635
#define SBE 11010048ull   // 43008*256 elements per split buffer

// ---------------- helpers ----------------
// fp32 -> fp16 pair with scaled residual: x ~= h0 + h1 * 2^-11  (error <= 2^-24 |x|)
__device__ __forceinline__ void split2(float y, unsigned short& h0, unsigned short& h1) {
  _Float16 b0 = (_Float16)y;
  float f0 = (float)b0;
  _Float16 b1 = (_Float16)((y - f0) * 2048.0f);
  h0 = __builtin_bit_cast(unsigned short, b0);
  h1 = __builtin_bit_cast(unsigned short, b1);
}

__device__ __forceinline__ void lds_hist_add(uint32_t* h, uint32_t bucket) {
  unsigned long long act = __ballot(1);
  int lane = (int)(threadIdx.x & 63u);
  int leader = __ffsll(act) - 1;
  uint32_t lb = (uint32_t)__shfl((int)bucket, leader, 64);
  unsigned long long same = __ballot(bucket == lb);
  if (same == act) {
    if (lane == leader) atomicAdd(&h[bucket], (uint32_t)__popcll(act));
  } else {
    atomicAdd(&h[bucket], 1u);
  }
}

// ---------------- zero borders/gaps of a split-pair region (px-major) ----------------
__global__ void k_zero(unsigned short* X0, unsigned short* X1) {
  int px = blockIdx.x * 256 + threadIdx.x;
  if (px >= 43008) return;
  int pi = 0;
#pragma unroll
  for (int i = 1; i < 10; i++) if (px >= cPBASE[i]) pi = i;
  const int l = pi >> 1;
  const int p = px - cPBASE[pi];
  const int W = cLW[l], H = cLH[l], PWl = W + 2;
  const int pr = p / PWl, pc = p - pr * PWl;
  if (pr >= 1 && pr <= H && pc >= 1 && pc <= W) return;  // interior: left alone
  s16x8 z = {0,0,0,0,0,0,0,0};
  size_t base = (size_t)px * 256;
#pragma unroll
  for (int k = 0; k < 32; k++) {
    *reinterpret_cast<s16x8*>(X0 + base + k*8) = z;
    *reinterpret_cast<s16x8*>(X1 + base + k*8) = z;
  }
}

// ---------------- stage inputs -> padded px-major fp16 splits ----------------
__global__ __launch_bounds__(256)
void k_prep(const float* __restrict__ p0, const float* __restrict__ p1,
            const float* __restrict__ p2, const float* __restrict__ p3,
            const float* __restrict__ p4,
            unsigned short* __restrict__ X0, unsigned short* __restrict__ X1) {
  int bx = blockIdx.x;
  int pi = 0;
#pragma unroll
  for (int i = 1; i < 10; i++) if (bx >= cRCUM[i]) pi = i;
  const int h = bx - cRCUM[pi];
  const int l = pi >> 1, bidx = pi & 1;
  const int W = cLW[l], HW = cLHW[l], PWl = W + 2;
  const int PB = cPBASE[pi];
  const float* src;
  if (l == 0) src = p0; else if (l == 1) src = p1; else if (l == 2) src = p2;
  else if (l == 3) src = p3; else src = p4;
  src += (size_t)bidx * 256 * HW;
  const int tid = threadIdx.x;
  __shared__ float tile[64][152];
  for (int c0 = 0; c0 < 256; c0 += 64) {
    {
      int c = tid >> 2, wq = tid & 3;
      for (int w = wq; w < W; w += 4)
        tile[c][w] = src[(size_t)(c0 + c) * HW + h * W + w];
    }
    __syncthreads();
    {
      int c8 = (tid & 7) * 8;
      for (int w = tid >> 3; w < W; w += 32) {
        size_t base = (size_t)(PB + (h + 1) * PWl + (w + 1)) * 256 + c0 + c8;
        unsigned short a0[8], a1[8];
#pragma unroll
        for (int j = 0; j < 8; j++) split2(tile[c8 + j][w], a0[j], a1[j]);
        *reinterpret_cast<s16x8*>(X0 + base) = *reinterpret_cast<s16x8*>(a0);
        *reinterpret_cast<s16x8*>(X1 + base) = *reinterpret_cast<s16x8*>(a1);
      }
    }
    __syncthreads();
  }
}

// ---------------- pack ALL weights -> fragment-order fp16 splits ----------------
// layout: [layer][(r*2+s)][ocf(16)][kc(8)][lane(64)][8]
__global__ void k_packall(const float* __restrict__ box_w, const float* __restrict__ cls_w,
                          const float* __restrict__ logit_w, unsigned short* __restrict__ wp) {
  const int layer = blockIdx.y;
  const int oc = blockIdx.x, c = threadIdx.x;
  const float* w; int Cout = 256;
  const size_t WSTRIDE = (size_t)256 * 2304;
  if (layer < 4)      w = box_w + (size_t)layer * WSTRIDE;
  else if (layer < 8) w = cls_w + (size_t)(layer - 4) * WSTRIDE;
  else { w = logit_w; Cout = NCLS; }
  if (oc >= Cout) return;
  unsigned short* wpL = wp + (size_t)layer * WLAYER;
  const int ocf = oc >> 4, ln = oc & 15;
  const int kc = c >> 5, kg = (c >> 3) & 3, e = c & 7;
  const int lane = kg * 16 + ln;
#pragma unroll
  for (int r = 0; r < 9; r++) {
    float v = w[((size_t)oc * 256 + c) * 9 + r];
    unsigned short h0, h1;
    split2(v, h0, h1);
    wpL[((((size_t)(r * 2 + 0) * 16 + ocf) * 8 + kc) * 64 + lane) * 8 + e] = h0;
    wpL[((((size_t)(r * 2 + 1) * 16 + ocf) * 8 + kc) * 64 + lane) * 8 + e] = h1;
  }
}

// ---------------- pack head weights -> wh[r][c][5] ----------------
__global__ void k_packhead(const float* __restrict__ ctw, const float* __restrict__ pdw,
                           float* __restrict__ wh) {
  const int r = blockIdx.x, c = threadIdx.x;
  float* d = &wh[((size_t)r * 256 + c) * 5];
  d[0] = ctw[c * 9 + r];
#pragma unroll
  for (int q = 0; q < 4; q++) d[1 + q] = pdw[(size_t)q * 2304 + c * 9 + r];
}

// ---------------- MFMA conv v4 (256-thr, fallback + logits) ----------------
struct MfArgs {
  const unsigned short *X0, *X1;
  const unsigned short *Wp;
  const float* bias;
  unsigned short *Y0, *Y1;
  float* actf;
  float* scores;
  const float* ctrp;
  uint32_t* hist;
};

template<int EPI>
__global__ __launch_bounds__(256, 2)
void conv_mfma(MfArgs a) {
  __shared__ __align__(16) unsigned short lds[18432];
  const int tid = threadIdx.x;
  const int lane = tid & 63;
  const int wid = tid >> 6;

  const int nwg = (EPI == 2) ? 336 : 672;
  const int id = blockIdx.x;
  const int w = (id & 7) * (nwg >> 3) + (id >> 3);
  const int oc0 = (EPI == 2) ? 0 : (w & 1) * 128;
  int bx = (EPI == 2) ? w : (w >> 1);

  int pi = 0;
#pragma unroll
  for (int i = 1; i < 10; i++) if (bx >= cCB[i]) pi = i;
  const int l = pi >> 1, bidx = pi & 1;
  const int pxb = bx - cCB[pi];
  const int px0 = pxb * 128;
  const int PB = cPBASE[pi];
  const int W = cLW[l], H = cLH[l], HW = cLHW[l], PWl = W + 2;

  int row_[2], g_[2];
#pragma unroll
  for (int d = 0; d < 2; d++) {
    int idx2 = tid + d * 256;
    row_[d] = idx2 >> 2;
    g_[d] = idx2 & 3;
  }

  const int wr = wid >> 1, wc = wid & 1;
  const int kg = lane >> 4, ln15 = lane & 15;
  int fA[4];
#pragma unroll
  for (int mt = 0; mt < 4; mt++) fA[mt] = (wr * 64 + mt * 16 + ln15) * 72 + kg * 8;
  const int ocfb = (oc0 >> 4) + wc * 4;

  f32x4 acc0[4][4], acc1[4][4];
#pragma unroll
  for (int mt = 0; mt < 4; mt++)
#pragma unroll
    for (int nt = 0; nt < 4; nt++) {
      acc0[mt][nt] = (f32x4){0.f, 0.f, 0.f, 0.f};
      acc1[mt][nt] = (f32x4){0.f, 0.f, 0.f, 0.f};
    }

  s16x8 ra[4];
  auto loadA = [&](int step) {
    const int rr = step >> 3;
    const int c0 = (step & 7) << 5;
    const int dh = rr / 3 - 1, dw = rr - (rr / 3) * 3 - 1;
    const long long OFF = (long long)(PB + px0 + dh * PWl + dw);
#pragma unroll
    for (int s = 0; s < 2; s++) {
      const unsigned short* Xs = (s == 0) ? a.X0 : a.X1;
#pragma unroll
      for (int d = 0; d < 2; d++)
        ra[s * 2 + d] = *reinterpret_cast<const s16x8*>(Xs + (OFF + row_[d]) * 256 + c0 + g_[d] * 8);
    }
  };
  auto writeA = [&](int buf) {
#pragma unroll
    for (int s = 0; s < 2; s++)
#pragma unroll
      for (int d = 0; d < 2; d++) {
        const int o = buf * 9216 + row_[d] * 72 + (s * 4 + g_[d]) * 8;
        *reinterpret_cast<s16x8*>(&lds[o]) = ra[s * 2 + d];
      }
  };
  auto loadB = [&](int step, f16x8* bv) {
    const int rr = step >> 3, cc = step & 7;
#pragma unroll
    for (int nt = 0; nt < 4; nt++) {
      const size_t bo = ((size_t)((rr * 2) * 16 + ocfb + nt) * 8 + cc) * 512 + lane * 8;
      bv[nt * 2 + 0] = *reinterpret_cast<const f16x8*>(a.Wp + bo);
      bv[nt * 2 + 1] = *reinterpret_cast<const f16x8*>(a.Wp + bo + 65536);
    }
  };
  auto mfmaStep = [&](int buf, const f16x8* bv) {
    f16x8 av[4][2];
#pragma unroll
    for (int mt = 0; mt < 4; mt++) {
      av[mt][0] = *reinterpret_cast<const f16x8*>(&lds[buf * 9216 + fA[mt]]);
      av[mt][1] = *reinterpret_cast<const f16x8*>(&lds[buf * 9216 + fA[mt] + 32]);
    }
#pragma unroll
    for (int mt = 0; mt < 4; mt++)
#pragma unroll
      for (int nt = 0; nt < 4; nt++) {
        acc0[mt][nt] = __builtin_amdgcn_mfma_f32_16x16x32_f16(av[mt][0], bv[nt * 2 + 0], acc0[mt][nt], 0, 0, 0);
        acc1[mt][nt] = __builtin_amdgcn_mfma_f32_16x16x32_f16(av[mt][0], bv[nt * 2 + 1], acc1[mt][nt], 0, 0, 0);
        acc1[mt][nt] = __builtin_amdgcn_mfma_f32_16x16x32_f16(av[mt][1], bv[nt * 2 + 0], acc1[mt][nt], 0, 0, 0);
      }
  };

  f16x8 bv0[8], bv1[8];
  loadA(0); writeA(0);
  loadA(1);
  loadB(0, bv0);
  __syncthreads();

  for (int sp = 0; sp < 72; sp += 2) {
    if (sp + 1 < 72) { writeA(1); loadB(sp + 1, bv1); }
    if (sp + 2 < 72) loadA(sp + 2);
    mfmaStep(0, bv0);
    __syncthreads();
    if (sp + 2 < 72) { writeA(0); loadB(sp + 2, bv0); }
    if (sp + 3 < 72) loadA(sp + 3);
    mfmaStep(1, bv1);
    __syncthreads();
  }

  // epilogue
  uint32_t* hh = nullptr;
  if (EPI == 2) {
    hh = reinterpret_cast<uint32_t*>(lds);
    for (int i = tid; i < 4096; i += 256) hh[i] = 0;
    __syncthreads();
  }
#pragma unroll
  for (int mt = 0; mt < 4; mt++) {
#pragma unroll
    for (int i = 0; i < 4; i++) {
      const int pxl = wr * 64 + mt * 16 + (lane >> 4) * 4 + i;
      const int p = px0 + pxl;
      const int pr = p / PWl, pc = p - pr * PWl;
      if (!(pr >= 1 && pr <= H && pc >= 1 && pc <= W)) continue;
      const int hw = (pr - 1) * W + (pc - 1);
#pragma unroll
      for (int nt = 0; nt < 4; nt++) {
        const int oc = oc0 + wc * 64 + nt * 16 + ln15;
        const float v = acc0[mt][nt][i] + acc1[mt][nt][i] * 4.8828125e-4f;
        if (EPI == 2) {
          if (oc < NCLS) {
            float y = v + a.bias[oc];
            float pcs = 1.0f / (1.0f + expf(-y));
            float s = pcs * a.ctrp[2 * cLCUM[l] + bidx * HW + hw];
            s = (s > 0.05f) ? s : 0.f;
            a.scores[(size_t)NCLS * (2 * cLCUM[l] + bidx * HW) + (size_t)oc * HW + hw] = s;
            lds_hist_add(hh, __float_as_uint(s) >> 20);
          }
        } else {
          float y = fmaxf(v + a.bias[oc], 0.f);
          if (EPI == 0) {
            size_t o = (size_t)(PB + p) * 256 + oc;
            unsigned short h0, h1;
            split2(y, h0, h1);
            a.Y0[o] = h0; a.Y1[o] = h1;
          } else {
            a.actf[(size_t)(PB + p) * 256 + oc] = y;
          }
        }
      }
    }
  }
  if (EPI == 2) {
    __syncthreads();
    uint32_t* gh = a.hist + (size_t)(l * 2 + bidx) * 4096;
    for (int i = tid; i < 4096; i += 256) { uint32_t v = hh[i]; if (v) atomicAdd(&gh[i], v); }
  }
}

// ---------------- merged two-tower conv: grid 1344, 256 thr, tower-per-XCD-half swizzle ----------------
struct Mf2Args {
  const unsigned short *X0a, *X1a, *X0b, *X1b;
  const unsigned short *Wpa, *Wpb;
  const float *ba, *bb;
  unsigned short *Y0a, *Y1a, *Y0b, *Y1b;
  float* actf;   // LAST: tower 0 writes fp32 act here
};

template<int LAST>
__global__ __launch_bounds__(256, 2)
void conv2_mfma(Mf2Args g) {
  __shared__ __align__(16) unsigned short lds[18432];
  const int tid = threadIdx.x;
  const int lane = tid & 63;
  const int wid = tid >> 6;

  // tower = XCD half: each XCD's L2 holds ONE tower's 2.25 MB weight pack (< 4 MB)
  const int id = blockIdx.x;
  const int xcd = id & 7;
  const int t = xcd >> 2;
  const int w = (xcd & 3) * 168 + (id >> 3);   // [0,672) within tower, bijective
  const int bx = w >> 1;
  const int oc0 = (w & 1) * 128;
  const unsigned short* X0 = t ? g.X0b : g.X0a;
  const unsigned short* X1 = t ? g.X1b : g.X1a;
  const unsigned short* Wp = t ? g.Wpb : g.Wpa;
  const float* bias = t ? g.bb : g.ba;

  int pi = 0;
#pragma unroll
  for (int i = 1; i < 10; i++) if (bx >= cCB[i]) pi = i;
  const int l = pi >> 1;
  const int pxb = bx - cCB[pi];
  const int px0 = pxb * 128;
  const int PB = cPBASE[pi];
  const int W = cLW[l], H = cLH[l], PWl = W + 2;

  int row_[2], g_[2];
#pragma unroll
  for (int d = 0; d < 2; d++) {
    int idx2 = tid + d * 256;
    row_[d] = idx2 >> 2;
    g_[d] = idx2 & 3;
  }

  const int wr = wid >> 1, wc = wid & 1;
  const int kg = lane >> 4, ln15 = lane & 15;
  int fA[4];
#pragma unroll
  for (int mt = 0; mt < 4; mt++) fA[mt] = (wr * 64 + mt * 16 + ln15) * 72 + kg * 8;
  const int ocfb = (oc0 >> 4) + wc * 4;

  f32x4 acc0[4][4], acc1[4][4];
#pragma unroll
  for (int mt = 0; mt < 4; mt++)
#pragma unroll
    for (int nt = 0; nt < 4; nt++) {
      acc0[mt][nt] = (f32x4){0.f, 0.f, 0.f, 0.f};
      acc1[mt][nt] = (f32x4){0.f, 0.f, 0.f, 0.f};
    }

  s16x8 ra[4];
  auto loadA = [&](int step) {
    const int rr = step >> 3;
    const int c0 = (step & 7) << 5;
    const int dh = rr / 3 - 1, dw = rr - (rr / 3) * 3 - 1;
    const long long OFF = (long long)(PB + px0 + dh * PWl + dw);
#pragma unroll
    for (int s = 0; s < 2; s++) {
      const unsigned short* Xs = (s == 0) ? X0 : X1;
#pragma unroll
      for (int d = 0; d < 2; d++)
        ra[s * 2 + d] = *reinterpret_cast<const s16x8*>(Xs + (OFF + row_[d]) * 256 + c0 + g_[d] * 8);
    }
  };
  auto writeA = [&](int buf) {
#pragma unroll
    for (int s = 0; s < 2; s++)
#pragma unroll
      for (int d = 0; d < 2; d++) {
        const int o = buf * 9216 + row_[d] * 72 + (s * 4 + g_[d]) * 8;
        *reinterpret_cast<s16x8*>(&lds[o]) = ra[s * 2 + d];
      }
  };
  auto loadB = [&](int step, f16x8* bv) {
    const int rr = step >> 3, cc = step & 7;
#pragma unroll
    for (int nt = 0; nt < 4; nt++) {
      const size_t bo = ((size_t)((rr * 2) * 16 + ocfb + nt) * 8 + cc) * 512 + lane * 8;
      bv[nt * 2 + 0] = *reinterpret_cast<const f16x8*>(Wp + bo);
      bv[nt * 2 + 1] = *reinterpret_cast<const f16x8*>(Wp + bo + 65536);
    }
  };
  auto mfmaStep = [&](int buf, const f16x8* bv) {
    f16x8 av[4][2];
#pragma unroll
    for (int mt = 0; mt < 4; mt++) {
      av[mt][0] = *reinterpret_cast<const f16x8*>(&lds[buf * 9216 + fA[mt]]);
      av[mt][1] = *reinterpret_cast<const f16x8*>(&lds[buf * 9216 + fA[mt] + 32]);
    }
#pragma unroll
    for (int mt = 0; mt < 4; mt++)
#pragma unroll
      for (int nt = 0; nt < 4; nt++) {
        acc0[mt][nt] = __builtin_amdgcn_mfma_f32_16x16x32_f16(av[mt][0], bv[nt * 2 + 0], acc0[mt][nt], 0, 0, 0);
        acc1[mt][nt] = __builtin_amdgcn_mfma_f32_16x16x32_f16(av[mt][0], bv[nt * 2 + 1], acc1[mt][nt], 0, 0, 0);
        acc1[mt][nt] = __builtin_amdgcn_mfma_f32_16x16x32_f16(av[mt][1], bv[nt * 2 + 0], acc1[mt][nt], 0, 0, 0);
      }
  };

  f16x8 bv0[8], bv1[8];
  loadA(0); writeA(0);
  loadA(1);
  loadB(0, bv0);
  __syncthreads();

  for (int sp = 0; sp < 72; sp += 2) {
    if (sp + 1 < 72) { writeA(1); loadB(sp + 1, bv1); }
    if (sp + 2 < 72) loadA(sp + 2);
    mfmaStep(0, bv0);
    __syncthreads();
    if (sp + 2 < 72) { writeA(0); loadB(sp + 2, bv0); }
    if (sp + 3 < 72) loadA(sp + 3);
    mfmaStep(1, bv1);
    __syncthreads();
  }

  // epilogue: relu+bias; tower0@LAST -> fp32 act, else fp16 split pair
  unsigned short* Y0 = t ? g.Y0b : g.Y0a;
  unsigned short* Y1 = t ? g.Y1b : g.Y1a;
#pragma unroll
  for (int mt = 0; mt < 4; mt++) {
#pragma unroll
    for (int i = 0; i < 4; i++) {
      const int pxl = wr * 64 + mt * 16 + (lane >> 4) * 4 + i;
      const int p = px0 + pxl;
      const int pr = p / PWl, pc = p - pr * PWl;
      if (!(pr >= 1 && pr <= H && pc >= 1 && pc <= W)) continue;
#pragma unroll
      for (int nt = 0; nt < 4; nt++) {
        const int oc = oc0 + wc * 64 + nt * 16 + ln15;
        const float v = acc0[mt][nt][i] + acc1[mt][nt][i] * 4.8828125e-4f;
        float y = fmaxf(v + bias[oc], 0.f);
        if (LAST && t == 0) {
          g.actf[(size_t)(PB + p) * 256 + oc] = y;
        } else {
          size_t o = (size_t)(PB + p) * 256 + oc;
          unsigned short h0, h1;
          split2(y, h0, h1);
          Y0[o] = h0; Y1[o] = h1;
        }
      }
    }
  }
}

// ---------------- ctr + reg head: wave-per-px over px-major fp32 act ----------------
__global__ __launch_bounds__(256)
void k_head2(const float* __restrict__ headact, const float* __restrict__ wh,
             const float* __restrict__ ctb, const float* __restrict__ pdb,
             const float* __restrict__ scl,
             float* __restrict__ ctrp, float* __restrict__ regb) {
  __shared__ float swh[11520];
  for (int i = threadIdx.x; i < 11520; i += 256) swh[i] = wh[i];
  int bx = blockIdx.x; int l = 0;
#pragma unroll
  for (int i = 1; i < 5; i++) if (bx >= cCPX64[i]) l = i;
  const int lblk = bx - cCPX64[l];
  const int H = cLH[l], W = cLW[l], HW = cLHW[l]; const int N = 2 * HW;
  const int lane = threadIdx.x & 63;
  const int wv = threadIdx.x >> 6;
  __syncthreads();
  const float bb0 = ctb[0], bb1 = pdb[0], bb2 = pdb[1], bb3 = pdb[2], bb4 = pdb[3];
  const float sc = scl[l];
  const int c4 = lane * 4;
  for (int t = 0; t < 16; ++t) {
    int px = lblk * 64 + wv * 16 + t;
    if (px >= N) break;
    int bb = px / HW; int hw = px - bb * HW; int hh = hw / W; int ww = hw - hh * W;
    const int PB = cPBASE[l * 2 + bb];
    float a0 = 0.f, a1 = 0.f, a2 = 0.f, a3 = 0.f, a4 = 0.f;
#pragma unroll
    for (int r = 0; r < 9; r++) {
      int dh = r / 3 - 1, dw = r % 3 - 1;
      int ih = hh + dh, iw = ww + dw;
      if (!(((unsigned)ih < (unsigned)H) && ((unsigned)iw < (unsigned)W))) continue;
      const float4 x = *reinterpret_cast<const float4*>(
          headact + (size_t)(PB + (ih + 1) * (W + 2) + (iw + 1)) * 256 + c4);
      const float* wr = &swh[(size_t)(r * 256 + c4) * 5];
      a0 = fmaf(x.x, wr[0],  a0); a1 = fmaf(x.x, wr[1],  a1); a2 = fmaf(x.x, wr[2],  a2);
      a3 = fmaf(x.x, wr[3],  a3); a4 = fmaf(x.x, wr[4],  a4);
      a0 = fmaf(x.y, wr[5],  a0); a1 = fmaf(x.y, wr[6],  a1); a2 = fmaf(x.y, wr[7],  a2);
      a3 = fmaf(x.y, wr[8],  a3); a4 = fmaf(x.y, wr[9],  a4);
      a0 = fmaf(x.z, wr[10], a0); a1 = fmaf(x.z, wr[11], a1); a2 = fmaf(x.z, wr[12], a2);
      a3 = fmaf(x.z, wr[13], a3); a4 = fmaf(x.z, wr[14], a4);
      a0 = fmaf(x.w, wr[15], a0); a1 = fmaf(x.w, wr[16], a1); a2 = fmaf(x.w, wr[17], a2);
      a3 = fmaf(x.w, wr[18], a3); a4 = fmaf(x.w, wr[19], a4);
    }
#pragma unroll
    for (int off = 32; off > 0; off >>= 1) {
      a0 += __shfl_xor(a0, off, 64); a1 += __shfl_xor(a1, off, 64); a2 += __shfl_xor(a2, off, 64);
      a3 += __shfl_xor(a3, off, 64); a4 += __shfl_xor(a4, off, 64);
    }
    if (lane == 0) {
      const int gi = 2 * cLCUM[l] + bb * HW + hw;
      ctrp[gi] = 1.0f / (1.0f + expf(-(a0 + bb0)));
      float* rg = regb + (size_t)gi * 4;
      rg[0] = fmaxf((a1 + bb1) * sc, 0.f);
      rg[1] = fmaxf((a2 + bb2) * sc, 0.f);
      rg[2] = fmaxf((a3 + bb3) * sc, 0.f);
      rg[3] = fmaxf((a4 + bb4) * sc, 0.f);
    }
  }
}

// ---------------- top-k pipeline ----------------
__global__ void k_init(uint32_t* __restrict__ hist, uint32_t* __restrict__ ctrA,
                       uint32_t* __restrict__ ctrB, uint32_t* __restrict__ survCnt) {
  int i = blockIdx.x * blockDim.x + threadIdx.x;
  if (i < 40960) hist[i] = 0;
  if (i < 10) { ctrA[i] = 0; ctrB[i] = 0; }
  if (i < 2) survCnt[i] = 0;
}

__global__ __launch_bounds__(256)
void k_select(const uint32_t* __restrict__ hist, int* __restrict__ meta) {
  const int sid = blockIdx.x;
  const uint32_t* gh = hist + (size_t)sid * 4096;
  __shared__ uint32_t ps[256];
  uint32_t sum = 0;
  for (int i = 0; i < 16; i++) sum += gh[threadIdx.x * 16 + i];
  ps[threadIdx.x] = sum;
  __syncthreads();
  if (threadIdx.x == 0) {
    uint32_t c = 0; int T = 0, m = 1000;
    for (int ch = 255; ch >= 0; --ch) {
      if (c + ps[ch] >= 1000u) {
        for (int t = ch * 16 + 15; t >= ch * 16; --t) {
          uint32_t hv = gh[t];
          if (c + hv >= 1000u) { T = t; m = (int)(1000u - c); break; }
          c += hv;
        }
        break;
      }
      c += ps[ch];
    }
    meta[sid * 4 + 0] = T;
    meta[sid * 4 + 1] = (int)c;
    meta[sid * 4 + 2] = m;
    meta[sid * 4 + 3] = (int)gh[T];
  }
}

// two-pass block-aggregated collect: 2 global atomics per block
__global__ __launch_bounds__(256)
void k_collect(const float* __restrict__ scores, const int* __restrict__ meta,
               unsigned long long* __restrict__ listA, unsigned long long* __restrict__ listB,
               uint32_t* __restrict__ ctrA, uint32_t* __restrict__ ctrB) {
  const int sid = blockIdx.y; const int l = sid >> 1, b = sid & 1;
  const int HW = cLHW[l]; const int size = NCLS * HW;
  const int base = blockIdx.x * 4096;
  if (base >= size) return;
  const size_t sbase = (size_t)NCLS * (2 * cLCUM[l] + b * HW);
  const float* sb = scores + sbase;
  unsigned long long* lB = listB + sbase;
  unsigned long long* lA = listA + (size_t)sid * 1024;
  const uint32_t T = (uint32_t)meta[sid * 4];
  const int lane = (int)(threadIdx.x & 63u);
  __shared__ uint32_t cA, cB, bA, bB;
  if (threadIdx.x == 0) { cA = 0; cB = 0; }
  __syncthreads();
  uint32_t wa = 0, wb = 0;
  for (int j = 0; j < 16; j++) {
    int i = base + threadIdx.x + j * 256;
    bool inb = (i < size);
    uint32_t bits = inb ? __float_as_uint(sb[i]) : 0u;
    uint32_t bkt = bits >> 20;
    unsigned long long mA = __ballot(inb && bkt > T);
    unsigned long long mB = __ballot(inb && bkt == T);
    if (lane == 0) { wa += (uint32_t)__popcll(mA); wb += (uint32_t)__popcll(mB); }
  }
  if (lane == 0) { if (wa) atomicAdd(&cA, wa); if (wb) atomicAdd(&cB, wb); }
  __syncthreads();
  if (threadIdx.x == 0) {
    bA = cA ? atomicAdd(&ctrA[sid], cA) : 0u;
    bB = cB ? atomicAdd(&ctrB[sid], cB) : 0u;
    cA = 0; cB = 0;
  }
  __syncthreads();
  for (int j = 0; j < 16; j++) {
    int i = base + threadIdx.x + j * 256;
    bool inb = (i < size);
    uint32_t bits = inb ? __float_as_uint(sb[i]) : 0u;
    uint32_t bkt = bits >> 20;
    bool pA = inb && bkt > T;
    bool pB = inb && bkt == T;
    unsigned long long key = 0;
    if (pA || pB) {
      int cls = i / HW; int hw = i - cls * HW;
      uint32_t idx = (uint32_t)(hw * NCLS + cls);
      key = ((unsigned long long)bits << 32) | (unsigned long long)(0xFFFFFFFFu - idx);
    }
    unsigned long long mA = __ballot(pA);
    unsigned long long mB = __ballot(pB);
    unsigned long long lt = (1ull << lane) - 1ull;
    if (mA) {
      int ld = __ffsll(mA) - 1;
      uint32_t wbs = 0;
      if (lane == ld) wbs = atomicAdd(&cA, (uint32_t)__popcll(mA));
      wbs = (uint32_t)__shfl((int)wbs, ld, 64);
      if (pA) {
        uint32_t pos = bA + wbs + (uint32_t)__popcll(mA & lt);
        if (pos < 1024u) lA[pos] = key;
      }
    }
    if (mB) {
      int ld = __ffsll(mB) - 1;
      uint32_t wbs = 0;
      if (lane == ld) wbs = atomicAdd(&cB, (uint32_t)__popcll(mB));
      wbs = (uint32_t)__shfl((int)wbs, ld, 64);
      if (pB) lB[bB + wbs + (uint32_t)__popcll(mB & lt)] = key;
    }
  }
}

__global__ __launch_bounds__(1024)
void k_refine(const int* __restrict__ meta, const unsigned long long* __restrict__ listB,
              unsigned long long* __restrict__ listA, uint32_t* __restrict__ ctrA) {
  const int sid = blockIdx.x; const int l = sid >> 1, b = sid & 1;
  const int HW = cLHW[l];
  const size_t sbase = (size_t)NCLS * (2 * cLCUM[l] + b * HW);
  const unsigned long long* lB = listB + sbase;
  const int nB = meta[sid * 4 + 3];
  int m = meta[sid * 4 + 2];
  __shared__ uint32_t h[256];
  __shared__ unsigned long long sPre;
  __shared__ int sM;
  __shared__ uint32_t sCnt;
  unsigned long long prefix = 0, mask = 0;
  for (int p = 7; p >= 0; --p) {
    for (int i = threadIdx.x; i < 256; i += 1024) h[i] = 0;
    __syncthreads();
    for (int i = threadIdx.x; i < nB; i += 1024) {
      unsigned long long k = lB[i];
      if ((k & mask) == prefix) {
        uint32_t bkt = (uint32_t)((k >> (p * 8)) & 255ull);
        lds_hist_add(h, bkt);
      }
    }
    __syncthreads();
    if (threadIdx.x == 0) {
      uint32_t c = 0; int sel = 0; int mnew = m;
      for (int t = 255; t >= 0; --t) {
        if (c + h[t] >= (uint32_t)m) { sel = t; mnew = m - (int)c; break; }
        c += h[t];
      }
      sPre = prefix | ((unsigned long long)sel << (p * 8));
      sM = mnew;
    }
    __syncthreads();
    prefix = sPre; m = sM;
    mask |= (0xFFull << (p * 8));
    __syncthreads();
  }
  if (threadIdx.x == 0) sCnt = ctrA[sid];
  __syncthreads();
  for (int i = threadIdx.x; i < nB; i += 1024) {
    unsigned long long k = lB[i];
    if (k >= prefix) {
      uint32_t pos = atomicAdd(&sCnt, 1u);
      if (pos < 1024u) listA[(size_t)sid * 1024 + pos] = k;
    }
  }
  __syncthreads();
  if (threadIdx.x == 0) ctrA[sid] = sCnt;
}

__global__ __launch_bounds__(256)
void k_sortdec(const unsigned long long* __restrict__ listA, const uint32_t* __restrict__ ctrA,
               const float* __restrict__ regb, float* __restrict__ cbox,
               float* __restrict__ cscr, float* __restrict__ ccls) {
  const int sid = blockIdx.x; const int l = sid >> 1, b = sid & 1;
  const int HW = cLHW[l], W = cLW[l];
  __shared__ unsigned long long key[1024];
  int n = (int)ctrA[sid]; if (n > 1024) n = 1024;
  for (int i = threadIdx.x; i < 1024; i += 256)
    key[i] = (i < n) ? listA[(size_t)sid * 1024 + i] : 0ull;
  __syncthreads();
  for (int len = 2; len <= 1024; len <<= 1) {
    for (int j = len >> 1; j > 0; j >>= 1) {
      for (int t = threadIdx.x; t < 512; t += 256) {
        int i = ((t & ~(j - 1)) << 1) | (t & (j - 1));
        int pp = i | j;
        unsigned long long a = key[i], bq = key[pp];
        bool desc = ((i & len) == 0);
        if ((a < bq) == desc) { key[i] = bq; key[pp] = a; }
      }
      __syncthreads();
    }
  }
  for (int r = threadIdx.x; r < 1000; r += 256) {
    unsigned long long k = key[r];
    uint32_t bits = (uint32_t)(k >> 32);
    uint32_t idx = 0xFFFFFFFFu - (uint32_t)(k & 0xFFFFFFFFull);
    float val = __uint_as_float(bits);
    float sc = sqrtf(fmaxf(val, 1e-12f));
    int cls = (int)(idx % NCLS); int loc = (int)(idx / NCLS);
    int hh = loc / W; int ww = loc - hh * W;
    float cx = (float)(ww * cLSTR[l] + (cLSTR[l] >> 1));
    float cy = (float)(hh * cLSTR[l] + (cLSTR[l] >> 1));
    const float* rg = regb + (size_t)(2 * cLCUM[l] + b * HW + loc) * 4;
    int slot = b * 5000 + l * 1000 + r;
    cbox[slot * 4 + 0] = cx - rg[0];
    cbox[slot * 4 + 1] = cy - rg[1];
    cbox[slot * 4 + 2] = cx + rg[2];
    cbox[slot * 4 + 3] = cy + rg[3];
    cscr[slot] = sc;
    ccls[slot] = (float)cls;
  }
}

// ---------------- NMS stage A: per-(class,batch) greedy NMS, capped at 100 ----------------
#define NMSC 1536
__global__ __launch_bounds__(256)
void k_nmscls(const float* __restrict__ cbox, const float* __restrict__ cscr,
              const float* __restrict__ ccls,
              unsigned long long* __restrict__ surv, uint32_t* __restrict__ survCnt) {
  const int cls = blockIdx.x;
  const int b = blockIdx.y;
  __shared__ unsigned short mslot[5024];
  __shared__ float ms[5024];
  __shared__ float kx1[NMSC], ky1[NMSC], kx2[NMSC], ky2[NMSC], kar[NMSC];
  __shared__ uint32_t mcnt;
  __shared__ int sPick; __shared__ float sPickV;
  __shared__ float pb[5];
  __shared__ float wvv[4]; __shared__ int wvi[4];
  if (threadIdx.x == 0) mcnt = 0;
  __syncthreads();
  const float fc = (float)cls;
  for (int j = threadIdx.x; j < 5000; j += 256) {
    if (ccls[b * 5000 + j] == fc) {
      uint32_t p = atomicAdd(&mcnt, 1u);
      mslot[p] = (unsigned short)j;
      ms[p] = cscr[b * 5000 + j];
    }
  }
  __syncthreads();
  const int n = (int)mcnt;
  if (n == 0) return;
  const float off = fc * 10000.0f;
  const int nc = n < NMSC ? n : NMSC;
  for (int i = threadIdx.x; i < nc; i += 256) {
    const float4 bq = *reinterpret_cast<const float4*>(cbox + ((size_t)b * 5000 + mslot[i]) * 4);
    float x1 = bq.x + off, y1 = bq.y + off, x2 = bq.z + off, y2 = bq.w + off;
    kx1[i] = x1; ky1[i] = y1; kx2[i] = x2; ky2[i] = y2; kar[i] = (x2 - x1) * (y2 - y1);
  }
  __syncthreads();
  const int lane = threadIdx.x & 63, wv = threadIdx.x >> 6;
  for (int it = 0; it < 100; ++it) {
    float best = -1.f; int bi = 0x7FFF; int bidx = 0;
    for (int i = threadIdx.x; i < n; i += 256) {
      float v = ms[i];
      int sl = mslot[i];
      if (v > best || (v == best && sl < bi)) { best = v; bi = sl; bidx = i; }
    }
    for (int o = 32; o > 0; o >>= 1) {
      float ov = __shfl_down(best, o, 64);
      int oi = __shfl_down(bi, o, 64);
      int ox = __shfl_down(bidx, o, 64);
      if (ov > best || (ov == best && oi < bi)) { best = ov; bi = oi; bidx = ox; }
    }
    if (lane == 0) { wvv[wv] = best; wvi[wv] = (bidx << 13) | bi; }
    __syncthreads();
    if (threadIdx.x == 0) {
      float bb = wvv[0]; int pk = wvi[0];
      for (int q = 1; q < 4; q++) {
        float v = wvv[q]; int c = wvi[q];
        if (v > bb || (v == bb && (c & 8191) < (pk & 8191))) { bb = v; pk = c; }
      }
      sPickV = bb; sPick = pk;
      if (bb >= 0.f) {
        int slot = pk & 8191;
        uint32_t bits = __float_as_uint(bb);
        uint32_t gslot = (uint32_t)(b * 5000 + slot);
        unsigned long long key = ((unsigned long long)bits << 32) |
                                 (unsigned long long)(0xFFFFFFFFu - gslot);
        uint32_t pos = atomicAdd(&survCnt[b], 1u);
        surv[(size_t)b * 5000 + pos] = key;
        const float4 bx = *reinterpret_cast<const float4*>(cbox + (size_t)gslot * 4);
        pb[0] = bx.x + off; pb[1] = bx.y + off; pb[2] = bx.z + off; pb[3] = bx.w + off;
        pb[4] = (pb[2] - pb[0]) * (pb[3] - pb[1]);
      }
    }
    __syncthreads();
    if (sPickV < 0.f) break;
    const int pidx = sPick >> 13;
    const float bx1 = pb[0], by1 = pb[1], bx2 = pb[2], by2 = pb[3], ba = pb[4];
    for (int i = threadIdx.x; i < n; i += 256) {
      float v = ms[i];
      if (v < 0.f) continue;
      float x1, y1, x2, y2, ar;
      if (i < NMSC) {
        x1 = kx1[i]; y1 = ky1[i]; x2 = kx2[i]; y2 = ky2[i]; ar = kar[i];
      } else {
        const float4 bq = *reinterpret_cast<const float4*>(cbox + ((size_t)b * 5000 + mslot[i]) * 4);
        x1 = bq.x + off; y1 = bq.y + off; x2 = bq.z + off; y2 = bq.w + off;
        ar = (x2 - x1) * (y2 - y1);
      }
      float ix1 = fmaxf(bx1, x1), iy1 = fmaxf(by1, y1);
      float ix2 = fminf(bx2, x2), iy2 = fminf(by2, y2);
      float iw = fmaxf(ix2 - ix1, 0.f), ih = fmaxf(iy2 - iy1, 0.f);
      float inter = iw * ih;
      float iou = inter / ((ba + ar - inter) + 1e-9f);
      if (iou > 0.6f || i == pidx) ms[i] = -1.0f;
    }
    __syncthreads();
  }
}

// ---------------- NMS stage B: top-100 survivors by key, write rows ----------------
__global__ __launch_bounds__(1024)
void k_nmsfinal(const unsigned long long* __restrict__ surv, const uint32_t* __restrict__ survCnt,
                const float* __restrict__ cbox, const float* __restrict__ ccls,
                float* __restrict__ out) {
  const int b = blockIdx.x;
  const int n = (int)survCnt[b];
  const unsigned long long* sv = surv + (size_t)b * 5000;
  const int m = n < 100 ? n : 100;
  __shared__ uint32_t h[256];
  __shared__ unsigned long long sPre; __shared__ int sM;
  __shared__ unsigned long long topk[128];
  __shared__ uint32_t tcnt;
  unsigned long long prefix = 0, mask = 0;
  int mm = m;
  if (m > 0) {
    for (int p = 7; p >= 0; --p) {
      for (int i = threadIdx.x; i < 256; i += 1024) h[i] = 0;
      __syncthreads();
      for (int i = threadIdx.x; i < n; i += 1024) {
        unsigned long long k = sv[i];
        if ((k & mask) == prefix) lds_hist_add(h, (uint32_t)((k >> (p * 8)) & 255ull));
      }
      __syncthreads();
      if (threadIdx.x == 0) {
        uint32_t c = 0; int sel = 0; int mnew = mm;
        for (int t = 255; t >= 0; --t) {
          if (c + h[t] >= (uint32_t)mm) { sel = t; mnew = mm - (int)c; break; }
          c += h[t];
        }
        sPre = prefix | ((unsigned long long)sel << (p * 8));
        sM = mnew;
      }
      __syncthreads();
      prefix = sPre; mm = sM;
      mask |= (0xFFull << (p * 8));
      __syncthreads();
    }
  }
  if (threadIdx.x == 0) tcnt = 0;
  for (int i = threadIdx.x; i < 128; i += 1024) topk[i] = 0;
  __syncthreads();
  if (m > 0) {
    for (int i = threadIdx.x; i < n; i += 1024) {
      unsigned long long k = sv[i];
      if (k >= prefix) {
        uint32_t p = atomicAdd(&tcnt, 1u);
        if (p < 128) topk[p] = k;
      }
    }
  }
  __syncthreads();
  for (int len = 2; len <= 128; len <<= 1) {
    for (int j = len >> 1; j > 0; j >>= 1) {
      for (int t = threadIdx.x; t < 64; t += 1024) {
        int i = ((t & ~(j - 1)) << 1) | (t & (j - 1));
        int pp = i | j;
        unsigned long long a = topk[i], bq = topk[pp];
        bool desc = ((i & len) == 0);
        if ((a < bq) == desc) { topk[i] = bq; topk[pp] = a; }
      }
      __syncthreads();
    }
  }
  if (threadIdx.x < 100) {
    int it = threadIdx.x;
    float* orow = out + ((size_t)b * 100 + it) * 6;
    if (it < m) {
      unsigned long long k = topk[it];
      uint32_t gslot = 0xFFFFFFFFu - (uint32_t)(k & 0xFFFFFFFFull);
      const float4 bx = *reinterpret_cast<const float4*>(cbox + (size_t)gslot * 4);
      orow[0] = bx.x; orow[1] = bx.y; orow[2] = bx.z; orow[3] = bx.w;
      orow[4] = __uint_as_float((uint32_t)(k >> 32));
      orow[5] = ccls[gslot];
    } else {
      orow[0] = 0.f; orow[1] = 0.f; orow[2] = 0.f;
      orow[3] = 0.f; orow[4] = 0.f; orow[5] = 0.f;
    }
  }
}

// ---------------- host launch ----------------
static inline size_t alignup(size_t x) { return (x + 255) & ~(size_t)255; }

extern "C" void kernel_launch(void* const* d_in, const int* in_sizes, int n_in,
                              void* d_out, int out_size, void* d_ws, size_t ws_size,
                              hipStream_t stream) {
  (void)in_sizes; (void)n_in; (void)out_size;
  const float* p0 = (const float*)d_in[0];
  const float* p1 = (const float*)d_in[1];
  const float* p2 = (const float*)d_in[2];
  const float* p3 = (const float*)d_in[3];
  const float* p4 = (const float*)d_in[4];
  const float* cls_w   = (const float*)d_in[5];
  const float* cls_b   = (const float*)d_in[6];
  const float* box_w   = (const float*)d_in[7];
  const float* box_b   = (const float*)d_in[8];
  const float* logit_w = (const float*)d_in[9];
  const float* logit_b = (const float*)d_in[10];
  const float* pred_w  = (const float*)d_in[11];
  const float* pred_b  = (const float*)d_in[12];
  const float* ctr_w   = (const float*)d_in[13];
  const float* ctr_b   = (const float*)d_in[14];
  const float* scales  = (const float*)d_in[15];

  char* base = (char*)d_ws;
  size_t off = 0;
  auto take = [&](size_t bytes) { void* p = base + off; off = alignup(off + bytes); return p; };
  float* regb = (float*)take((size_t)4 * 2 * TOTHW * 4);
  float* ctrp = (float*)take((size_t)2 * TOTHW * 4);
  uint32_t* hist = (uint32_t*)take((size_t)40960 * 4);
  int* meta = (int*)take((size_t)40 * 4);
  uint32_t* ctrA = (uint32_t*)take(256);
  uint32_t* ctrB = (uint32_t*)take(256);
  uint32_t* survCnt = (uint32_t*)take(256);
  unsigned long long* listA = (unsigned long long*)take((size_t)10 * 1024 * 8);
  unsigned long long* surv = (unsigned long long*)take((size_t)2 * 5000 * 8);
  float* cbox = (float*)take((size_t)2 * 5000 * 16);
  float* cscr = (float*)take((size_t)2 * 5000 * 4);
  float* ccls = (float*)take((size_t)2 * 5000 * 4);
  float* wh   = (float*)take((size_t)9 * 256 * 5 * 4);
  unsigned short* wpackF = (unsigned short*)take((size_t)9 * WLAYER * 2);
  unsigned short* P_0 = (unsigned short*)take(SBE * 2);   // pair A
  unsigned short* P_1 = (unsigned short*)take(SBE * 2);
  unsigned short* R1_0 = (unsigned short*)take(SBE * 2);  // pair B
  unsigned short* R1_1 = (unsigned short*)take(SBE * 2);
  unsigned short* R2_0 = (unsigned short*)take(SBE * 2);  // pair C
  unsigned short* R2_1 = (unsigned short*)take(SBE * 2);
  (void)take(65536);                                 // halo-read safety pad
  unsigned short* D_0 = (unsigned short*)take(SBE * 2);   // pair D (merged mode only)
  unsigned short* D_1 = (unsigned short*)take(SBE * 2);
  (void)take(65536);                                 // halo pad after D
  const bool merged = (ws_size >= off);              // constant across calls -> graph-safe

  float* scores = (float*)R1_0;                      // B region free when logits runs
  unsigned long long* listB = (unsigned long long*)R2_0;  // C region free at collect

  hipLaunchKernelGGL(k_init, dim3(160), dim3(256), 0, stream, hist, ctrA, ctrB, survCnt);
  hipLaunchKernelGGL(k_packhead, dim3(9), dim3(256), 0, stream, ctr_w, pred_w, wh);
  hipLaunchKernelGGL(k_packall, dim3(256, 9), dim3(256), 0, stream, box_w, cls_w, logit_w, wpackF);
  hipLaunchKernelGGL(k_zero, dim3(168), dim3(256), 0, stream, P_0, P_1);
  hipLaunchKernelGGL(k_zero, dim3(168), dim3(256), 0, stream, R1_0, R1_1);
  hipLaunchKernelGGL(k_zero, dim3(168), dim3(256), 0, stream, R2_0, R2_1);
  if (merged) hipLaunchKernelGGL(k_zero, dim3(168), dim3(256), 0, stream, D_0, D_1);
  hipLaunchKernelGGL(k_prep, dim3(390), dim3(256), 0, stream, p0, p1, p2, p3, p4, P_0, P_1);

  auto runConv = [&](int epi, int layer, const unsigned short* x0, const unsigned short* x1,
                     const float* bias, unsigned short* y0, unsigned short* y1,
                     float* af, float* sc) {
    MfArgs a;
    a.X0 = x0; a.X1 = x1; a.Wp = wpackF + (size_t)layer * WLAYER; a.bias = bias;
    a.Y0 = y0; a.Y1 = y1; a.actf = af; a.scores = sc; a.ctrp = ctrp;
    a.hist = hist;
    if (epi == 0)      hipLaunchKernelGGL(conv_mfma<0>, dim3(672), dim3(256), 0, stream, a);
    else if (epi == 1) hipLaunchKernelGGL(conv_mfma<1>, dim3(672), dim3(256), 0, stream, a);
    else               hipLaunchKernelGGL(conv_mfma<2>, dim3(336), dim3(256), 0, stream, a);
  };

  if (merged) {
    // both towers per dispatch, 256-thr blocks, grid 1344: A=P, B=R1, C=R2, D
    auto run2 = [&](int last, int layer,
                    const unsigned short* xa0, const unsigned short* xa1,
                    const unsigned short* xb0, const unsigned short* xb1,
                    unsigned short* ya0, unsigned short* ya1,
                    unsigned short* yb0, unsigned short* yb1, float* af) {
      Mf2Args g;
      g.X0a = xa0; g.X1a = xa1; g.X0b = xb0; g.X1b = xb1;
      g.Wpa = wpackF + (size_t)layer * WLAYER;
      g.Wpb = wpackF + (size_t)(4 + layer) * WLAYER;
      g.ba = box_b + layer * 256; g.bb = cls_b + layer * 256;
      g.Y0a = ya0; g.Y1a = ya1; g.Y0b = yb0; g.Y1b = yb1; g.actf = af;
      if (last) hipLaunchKernelGGL(conv2_mfma<1>, dim3(1344), dim3(256), 0, stream, g);
      else      hipLaunchKernelGGL(conv2_mfma<0>, dim3(1344), dim3(256), 0, stream, g);
    };
    // L0: box A->B, cls A->C
    run2(0, 0, P_0, P_1, P_0, P_1, R1_0, R1_1, R2_0, R2_1, nullptr);
    // L1: box B->D, cls C->A
    run2(0, 1, R1_0, R1_1, R2_0, R2_1, D_0, D_1, P_0, P_1, nullptr);
    // L2: box D->B, cls A->C
    run2(0, 2, D_0, D_1, P_0, P_1, R1_0, R1_1, R2_0, R2_1, nullptr);
    // L3: box B->headact(D fp32), cls C->A
    run2(1, 3, R1_0, R1_1, R2_0, R2_1, nullptr, nullptr, P_0, P_1, (float*)D_0);
    hipLaunchKernelGGL(k_head2, dim3(NPXB64), dim3(256), 0, stream, (const float*)D_0, wh,
                       ctr_b, pred_b, scales, ctrp, regb);
    // logits: reads A (cls final act), writes scores (B region)
    runConv(2, 8, P_0, P_1, logit_b, nullptr, nullptr, nullptr, scores);
  } else {
    float* headact = (float*)R2_0;   // spans R2 pair exactly
    // ---- box tower: P -> R1 -> R2 -> R1 -> headact(R2 region, fp32) ----
    runConv(0, 0, P_0,  P_1,  box_b + 0,   R1_0, R1_1, nullptr, nullptr);
    runConv(0, 1, R1_0, R1_1, box_b + 256, R2_0, R2_1, nullptr, nullptr);
    runConv(0, 2, R2_0, R2_1, box_b + 512, R1_0, R1_1, nullptr, nullptr);
    runConv(1, 3, R1_0, R1_1, box_b + 768, nullptr, nullptr, headact, nullptr);
    hipLaunchKernelGGL(k_head2, dim3(NPXB64), dim3(256), 0, stream, headact, wh, ctr_b,
                       pred_b, scales, ctrp, regb);
    hipLaunchKernelGGL(k_zero, dim3(168), dim3(256), 0, stream, R2_0, R2_1);
    // ---- cls tower: P -> R1 -> R2 -> R1 -> R2 -> scores(R1 region) ----
    runConv(0, 4, P_0,  P_1,  cls_b + 0,   R1_0, R1_1, nullptr, nullptr);
    runConv(0, 5, R1_0, R1_1, cls_b + 256, R2_0, R2_1, nullptr, nullptr);
    runConv(0, 6, R2_0, R2_1, cls_b + 512, R1_0, R1_1, nullptr, nullptr);
    runConv(0, 7, R1_0, R1_1, cls_b + 768, R2_0, R2_1, nullptr, nullptr);
    runConv(2, 8, R2_0, R2_1, logit_b, nullptr, nullptr, nullptr, scores);
  }

  // ---- top-k + decode + NMS ----
  hipLaunchKernelGGL(k_select,  dim3(10), dim3(256), 0, stream, hist, meta);
  hipLaunchKernelGGL(k_collect, dim3(297, 10), dim3(256), 0, stream, scores, meta, listA, listB, ctrA, ctrB);
  hipLaunchKernelGGL(k_refine,  dim3(10), dim3(1024), 0, stream, meta, listB, listA, ctrA);
  hipLaunchKernelGGL(k_sortdec, dim3(10), dim3(256), 0, stream, listA, ctrA, regb, cbox, cscr, ccls);
  hipLaunchKernelGGL(k_nmscls,  dim3(NCLS, 2), dim3(256), 0, stream, cbox, cscr, ccls, surv, survCnt);
  hipLaunchKernelGGL(k_nmsfinal, dim3(2), dim3(1024), 0, stream, surv, survCnt, cbox, ccls, (float*)d_out);
}